// Round 1
// baseline (666.548 us; speedup 1.0000x reference)
//
#include <hip/hip_runtime.h>
#include <hip/hip_bf16.h>

#define NB 2
#define NS 12
#define NN 800
#define NH 64      // hidden
#define HEADS 8
#define DH 8
#define NBS (NB*NS)        // 24
#define NR (NB*NS*NN)      // 19200 rows

// ---------------------------------------------------------------------------
// 1) xs = x*(1+0.3*x[..,62]*exp(-x[..,63]/60));  h0 = xs @ W_gp + b_gp
// ---------------------------------------------------------------------------
__global__ __launch_bounds__(256) void k_scale_gp(
    const float* __restrict__ x, const float* __restrict__ W,
    const float* __restrict__ bias, float* __restrict__ out) {
  __shared__ float Ws[64][64];
  __shared__ float xr[16][64];
  __shared__ float sf[16];
  int tid = threadIdx.x;
  int col = tid & 63, rg = tid >> 6;
  int row0 = blockIdx.x * 16;
  for (int i = tid; i < 4096; i += 256) Ws[i >> 6][i & 63] = W[i];
  for (int i = tid; i < 1024; i += 256)
    xr[i >> 6][i & 63] = x[(size_t)row0 * 64 + i];
  __syncthreads();
  if (tid < 16) {
    float a = xr[tid][62] * __expf(-xr[tid][63] * (1.0f / 60.0f));
    sf[tid] = 1.0f + 0.3f * a;
  }
  __syncthreads();
  float bv = bias[col];
  for (int rr = 0; rr < 4; ++rr) {
    int r = rg * 4 + rr;
    float acc = 0.f;
#pragma unroll
    for (int i = 0; i < 64; ++i) acc += xr[r][i] * Ws[i][col];
    out[(size_t)(row0 + r) * 64 + col] = acc * sf[r] + bv;
  }
}

// ---------------------------------------------------------------------------
// 2) h = relu(adj @ h)   (+x residual when LAST)
// ---------------------------------------------------------------------------
template <bool LAST>
__global__ __launch_bounds__(256) void k_prop(
    const float* __restrict__ adj, const float* __restrict__ hin,
    const float* __restrict__ x, float* __restrict__ hout) {
  __shared__ float hs[80][64];
  __shared__ float as[16][80];
  int tid = threadIdx.x;
  int col = tid & 63, rg = tid >> 6;
  int bs = blockIdx.x;           // 0..23
  int b = bs / NS;
  int n0 = blockIdx.y * 16;
  const float* hbase = hin + (size_t)bs * NN * 64;
  const float* abase = adj + (size_t)b * NN * NN;
  float acc[4] = {0.f, 0.f, 0.f, 0.f};
  for (int m0 = 0; m0 < NN; m0 += 80) {
    __syncthreads();
    for (int i = tid; i < 80 * 64; i += 256) {
      int m = i >> 6, c = i & 63;
      hs[m][c] = hbase[(size_t)(m0 + m) * 64 + c];
    }
    for (int i = tid; i < 16 * 80; i += 256) {
      int r = i / 80, m = i % 80;
      as[r][m] = abase[(size_t)(n0 + r) * NN + (m0 + m)];
    }
    __syncthreads();
#pragma unroll 4
    for (int m = 0; m < 80; ++m) {
      float hv = hs[m][col];
#pragma unroll
      for (int rr = 0; rr < 4; ++rr) acc[rr] += as[rg * 4 + rr][m] * hv;
    }
  }
  for (int rr = 0; rr < 4; ++rr) {
    int n = n0 + rg * 4 + rr;
    float v = fmaxf(acc[rr], 0.f);
    size_t o = ((size_t)bs * NN + n) * 64 + col;
    if (LAST) v += x[o];
    hout[o] = v;
  }
}

// ---------------------------------------------------------------------------
// 3) fused Q/K/V linear: {Q,K,V} = X@W* + b*
// ---------------------------------------------------------------------------
__global__ __launch_bounds__(256) void k_qkv3(
    const float* __restrict__ X, const float* __restrict__ Wq,
    const float* __restrict__ Wk, const float* __restrict__ Wv,
    const float* __restrict__ bq, const float* __restrict__ bk,
    const float* __restrict__ bv, float* __restrict__ Q, float* __restrict__ K,
    float* __restrict__ V) {
  __shared__ float Wqs[64][64], Wks[64][64], Wvs[64][64];
  __shared__ float xr[16][64];
  int tid = threadIdx.x;
  int col = tid & 63, rg = tid >> 6;
  int row0 = blockIdx.x * 16;
  for (int i = tid; i < 4096; i += 256) {
    Wqs[i >> 6][i & 63] = Wq[i];
    Wks[i >> 6][i & 63] = Wk[i];
    Wvs[i >> 6][i & 63] = Wv[i];
  }
  for (int i = tid; i < 1024; i += 256)
    xr[i >> 6][i & 63] = X[(size_t)row0 * 64 + i];
  __syncthreads();
  float bqv = bq[col], bkv = bk[col], bvv = bv[col];
  for (int rr = 0; rr < 4; ++rr) {
    int r = rg * 4 + rr;
    float aq = bqv, ak = bkv, av = bvv;
#pragma unroll
    for (int i = 0; i < 64; ++i) {
      float xv = xr[r][i];
      aq += xv * Wqs[i][col];
      ak += xv * Wks[i][col];
      av += xv * Wvs[i][col];
    }
    size_t o = (size_t)(row0 + r) * 64 + col;
    Q[o] = aq;
    K[o] = ak;
    V[o] = av;
  }
}

// ---------------------------------------------------------------------------
// 4) spatial attention (flash, one query row per thread), L = 800
// ---------------------------------------------------------------------------
__global__ __launch_bounds__(256) void k_sattn(const float* __restrict__ Q,
                                               const float* __restrict__ K,
                                               const float* __restrict__ V,
                                               float* __restrict__ O) {
  const int bs = blockIdx.x, h = blockIdx.y;
  const int l = blockIdx.z * 256 + threadIdx.x;
  __shared__ float Ks[160][8];
  __shared__ float Vs[160][8];
  const size_t base = (size_t)bs * NN * 64 + h * DH;
  bool act = l < NN;
  int lq = act ? l : 0;
  float q[8];
#pragma unroll
  for (int d = 0; d < 8; ++d)
    q[d] = Q[base + (size_t)lq * 64 + d] * 0.35355339059327373f;
  float m = -1e30f, lsum = 0.f;
  float o[8] = {0, 0, 0, 0, 0, 0, 0, 0};
  for (int k0 = 0; k0 < NN; k0 += 160) {
    __syncthreads();
    for (int i = threadIdx.x; i < 160 * 8; i += 256) {
      int kk = i >> 3, d = i & 7;
      Ks[kk][d] = K[base + (size_t)(k0 + kk) * 64 + d];
      Vs[kk][d] = V[base + (size_t)(k0 + kk) * 64 + d];
    }
    __syncthreads();
    for (int kk = 0; kk < 160; ++kk) {
      float s = 0.f;
#pragma unroll
      for (int d = 0; d < 8; ++d) s += q[d] * Ks[kk][d];
      float mn = fmaxf(m, s);
      float corr = __expf(m - mn);
      float p = __expf(s - mn);
      lsum = lsum * corr + p;
#pragma unroll
      for (int d = 0; d < 8; ++d) o[d] = o[d] * corr + p * Vs[kk][d];
      m = mn;
    }
  }
  if (act) {
    float inv = 1.f / lsum;
#pragma unroll
    for (int d = 0; d < 8; ++d) O[base + (size_t)l * 64 + d] = o[d] * inv;
  }
}

// ---------------------------------------------------------------------------
// 5) y = LN(X@W + b + res; g, be)   (wave per row)
// ---------------------------------------------------------------------------
__global__ __launch_bounds__(256) void k_projln(
    const float* __restrict__ X, const float* __restrict__ W,
    const float* __restrict__ bias, const float* __restrict__ res,
    const float* __restrict__ g, const float* __restrict__ be,
    float* __restrict__ out) {
  __shared__ float Ws[64][64];
  int tid = threadIdx.x;
  int lane = tid & 63, w = tid >> 6;
  for (int i = tid; i < 4096; i += 256) Ws[i >> 6][i & 63] = W[i];
  __syncthreads();
  int row = blockIdx.x * 4 + w;
  float xv = X[(size_t)row * 64 + lane];
  float acc = bias[lane];
#pragma unroll
  for (int i = 0; i < 64; ++i) acc += __shfl(xv, i, 64) * Ws[i][lane];
  acc += res[(size_t)row * 64 + lane];
  float s = acc;
#pragma unroll
  for (int off = 32; off; off >>= 1) s += __shfl_xor(s, off, 64);
  float mean = s * (1.f / 64.f);
  float d = acc - mean;
  float v = d * d;
#pragma unroll
  for (int off = 32; off; off >>= 1) v += __shfl_xor(v, off, 64);
  float rstd = rsqrtf(v * (1.f / 64.f) + 1e-5f);
  out[(size_t)row * 64 + lane] = d * rstd * g[lane] + be[lane];
}

// ---------------------------------------------------------------------------
// 6) temporal attention: one block per (b,n), L = 12
// ---------------------------------------------------------------------------
__global__ __launch_bounds__(256) void k_tattn(const float* __restrict__ Q,
                                               const float* __restrict__ K,
                                               const float* __restrict__ V,
                                               float* __restrict__ O) {
  int b = blockIdx.x / NN, n = blockIdx.x % NN;
  __shared__ float Qs[12][64], Ks[12][64], Vs[12][64];
  int tid = threadIdx.x;
  for (int i = tid; i < 12 * 64; i += 256) {
    int s = i >> 6, c = i & 63;
    size_t idx = (((size_t)b * NS + s) * NN + n) * 64 + c;
    Qs[s][c] = Q[idx];
    Ks[s][c] = K[idx];
    Vs[s][c] = V[idx];
  }
  __syncthreads();
  for (int wi = tid; wi < 12 * 64; wi += 256) {
    int l = wi >> 6, c = wi & 63;
    int h8 = c & 56;
    float sc[12];
    float mx = -1e30f;
#pragma unroll
    for (int m = 0; m < 12; ++m) {
      float s = 0.f;
#pragma unroll
      for (int d = 0; d < 8; ++d) s += Qs[l][h8 + d] * Ks[m][h8 + d];
      s *= 0.35355339059327373f;
      sc[m] = s;
      mx = fmaxf(mx, s);
    }
    float sum = 0.f;
#pragma unroll
    for (int m = 0; m < 12; ++m) {
      sc[m] = __expf(sc[m] - mx);
      sum += sc[m];
    }
    float inv = 1.f / sum;
    float o = 0.f;
#pragma unroll
    for (int m = 0; m < 12; ++m) o += sc[m] * Vs[m][c];
    size_t idx = (((size_t)b * NS + l) * NN + n) * 64 + c;
    O[idx] = o * inv;
  }
}

// ---------------------------------------------------------------------------
// 7) plain LN (wave per row)
// ---------------------------------------------------------------------------
__global__ __launch_bounds__(256) void k_ln(const float* __restrict__ X,
                                            const float* __restrict__ g,
                                            const float* __restrict__ be,
                                            float* __restrict__ out) {
  int tid = threadIdx.x;
  int lane = tid & 63, w = tid >> 6;
  int row = blockIdx.x * 4 + w;
  float acc = X[(size_t)row * 64 + lane];
  float s = acc;
#pragma unroll
  for (int off = 32; off; off >>= 1) s += __shfl_xor(s, off, 64);
  float mean = s * (1.f / 64.f);
  float d = acc - mean;
  float v = d * d;
#pragma unroll
  for (int off = 32; off; off >>= 1) v += __shfl_xor(v, off, 64);
  float rstd = rsqrtf(v * (1.f / 64.f) + 1e-5f);
  out[(size_t)row * 64 + lane] = d * rstd * g[lane] + be[lane];
}

// ---------------------------------------------------------------------------
// 8) FFN layer 1: hid = relu(X@W1 + b1), W1 is 64x256
// ---------------------------------------------------------------------------
__global__ __launch_bounds__(256) void k_ffn1(const float* __restrict__ X,
                                              const float* __restrict__ W1,
                                              const float* __restrict__ b1,
                                              float* __restrict__ Hid) {
  __shared__ float Ws[64][256];  // 64 KB
  int tid = threadIdx.x;
  for (int i = tid; i < 64 * 256; i += 256) Ws[i >> 8][i & 255] = W1[i];
  __syncthreads();
  int row0 = blockIdx.x * 16;
  float bv = b1[tid];
  for (int r = 0; r < 16; ++r) {
    const float* xr = X + (size_t)(row0 + r) * 64;
    float acc = bv;
#pragma unroll
    for (int i = 0; i < 64; ++i) acc += xr[i] * Ws[i][tid];
    Hid[(size_t)(row0 + r) * 256 + tid] = fmaxf(acc, 0.f);
  }
}

// ---------------------------------------------------------------------------
// 9) FFN layer 2 + residual + final LN:  out = LN(hid@W2 + b2 + res; g2, be2)
// ---------------------------------------------------------------------------
__global__ __launch_bounds__(256) void k_ffn2ln(
    const float* __restrict__ Hd, const float* __restrict__ W2,
    const float* __restrict__ b2, const float* __restrict__ res,
    const float* __restrict__ g, const float* __restrict__ be,
    float* __restrict__ out) {
  __shared__ float Ws[256][64];  // 64 KB
  int tid = threadIdx.x;
  int lane = tid & 63, w = tid >> 6;
  for (int i = tid; i < 256 * 64; i += 256) Ws[i >> 6][i & 63] = W2[i];
  __syncthreads();
  int row = blockIdx.x * 4 + w;
  const float* hr = Hd + (size_t)row * 256;
  float acc = b2[lane] + res[(size_t)row * 64 + lane];
#pragma unroll
  for (int c = 0; c < 4; ++c) {
    float hv = hr[c * 64 + lane];
#pragma unroll
    for (int i = 0; i < 64; ++i) acc += __shfl(hv, i, 64) * Ws[c * 64 + i][lane];
  }
  float s = acc;
#pragma unroll
  for (int off = 32; off; off >>= 1) s += __shfl_xor(s, off, 64);
  float mean = s * (1.f / 64.f);
  float d = acc - mean;
  float v = d * d;
#pragma unroll
  for (int off = 32; off; off >>= 1) v += __shfl_xor(v, off, 64);
  float rstd = rsqrtf(v * (1.f / 64.f) + 1e-5f);
  out[(size_t)row * 64 + lane] = d * rstd * g[lane] + be[lane];
}

// ---------------------------------------------------------------------------
extern "C" void kernel_launch(void* const* d_in, const int* in_sizes, int n_in,
                              void* d_out, int out_size, void* d_ws,
                              size_t ws_size, hipStream_t stream) {
  const float* x = (const float*)d_in[0];
  const float* adj = (const float*)d_in[1];
  const float* W_gp = (const float*)d_in[2];
  const float* b_gp = (const float*)d_in[3];
  const float* Wq_s = (const float*)d_in[4];
  const float* Wk_s = (const float*)d_in[5];
  const float* Wv_s = (const float*)d_in[6];
  const float* Wo_s = (const float*)d_in[7];
  const float* bq_s = (const float*)d_in[8];
  const float* bk_s = (const float*)d_in[9];
  const float* bv_s = (const float*)d_in[10];
  const float* bo_s = (const float*)d_in[11];
  const float* g_s = (const float*)d_in[12];
  const float* be_s = (const float*)d_in[13];
  const float* Wq_t = (const float*)d_in[14];
  const float* Wk_t = (const float*)d_in[15];
  const float* Wv_t = (const float*)d_in[16];
  const float* Wo_t = (const float*)d_in[17];
  const float* bq_t = (const float*)d_in[18];
  const float* bk_t = (const float*)d_in[19];
  const float* bv_t = (const float*)d_in[20];
  const float* bo_t = (const float*)d_in[21];
  const float* g_t = (const float*)d_in[22];
  const float* be_t = (const float*)d_in[23];
  const float* W1 = (const float*)d_in[24];
  const float* b1 = (const float*)d_in[25];
  const float* W2 = (const float*)d_in[26];
  const float* b2 = (const float*)d_in[27];
  const float* g1 = (const float*)d_in[28];
  const float* be1 = (const float*)d_in[29];
  const float* g2 = (const float*)d_in[30];
  const float* be2 = (const float*)d_in[31];
  float* out = (float*)d_out;

  float* ws = (float*)d_ws;
  const size_t U = (size_t)NR * 64;  // 1,228,800 floats
  float* A = ws + 0 * U;
  float* Bb = ws + 1 * U;
  float* C = ws + 2 * U;
  float* D = ws + 3 * U;
  float* P = ws + 4 * U;
  float* HID = ws + 5 * U;  // NR x 256 = 4U

  dim3 blk(256);
  // 1) scale + graph linear -> A
  k_scale_gp<<<NR / 16, blk, 0, stream>>>(x, W_gp, b_gp, A);
  // 2) 3 propagation steps, residual fused into last -> P
  k_prop<false><<<dim3(NBS, NN / 16), blk, 0, stream>>>(adj, A, x, Bb);
  k_prop<false><<<dim3(NBS, NN / 16), blk, 0, stream>>>(adj, Bb, x, A);
  k_prop<true><<<dim3(NBS, NN / 16), blk, 0, stream>>>(adj, A, x, P);
  // 3) spatial QKV -> A,Bb,C ; attn -> D ; proj+LN -> A (res = P)
  k_qkv3<<<NR / 16, blk, 0, stream>>>(P, Wq_s, Wk_s, Wv_s, bq_s, bk_s, bv_s, A,
                                      Bb, C);
  k_sattn<<<dim3(NBS, HEADS, 4), blk, 0, stream>>>(A, Bb, C, D);
  k_projln<<<NR / 4, blk, 0, stream>>>(D, Wo_s, bo_s, P, g_s, be_s, A);
  // 4) temporal QKV -> Bb,C,D ; attn -> P ; proj+LN -> Bb (res = A)
  k_qkv3<<<NR / 16, blk, 0, stream>>>(A, Wq_t, Wk_t, Wv_t, bq_t, bk_t, bv_t, Bb,
                                      C, D);
  k_tattn<<<NB * NN, blk, 0, stream>>>(Bb, C, D, P);
  k_projln<<<NR / 4, blk, 0, stream>>>(P, Wo_t, bo_t, A, g_t, be_t, Bb);
  // 5) FFN: LN1 -> C ; hid -> HID ; W2 + residual + final LN -> out
  k_ln<<<NR / 4, blk, 0, stream>>>(Bb, g1, be1, C);
  k_ffn1<<<NR / 16, blk, 0, stream>>>(C, W1, b1, HID);
  k_ffn2ln<<<NR / 4, blk, 0, stream>>>(HID, W2, b2, Bb, g2, be2, out);
}

// Round 2
// 465.194 us; speedup vs baseline: 1.4328x; 1.4328x over previous
//
#include <hip/hip_runtime.h>
#include <hip/hip_bf16.h>

#define NB 2
#define NS 12
#define NN 800
#define NH 64      // hidden
#define HEADS 8
#define DH 8
#define NBS (NB*NS)        // 24
#define NR (NB*NS*NN)      // 19200 rows

typedef __attribute__((ext_vector_type(4))) float f32x4;
typedef __attribute__((ext_vector_type(4))) short s16x4;
typedef __attribute__((ext_vector_type(8))) short s16x8;

static __device__ __forceinline__ unsigned short f2bf(float f) {
  union { float f; unsigned u; } v; v.f = f;
  unsigned r = (v.u + 0x7FFFu + ((v.u >> 16) & 1u)) >> 16;
  return (unsigned short)r;
}

// ---------------------------------------------------------------------------
// 0) adj f32 -> bf16 (once per call)
// ---------------------------------------------------------------------------
__global__ __launch_bounds__(256) void k_adjbf(const float* __restrict__ adj,
                                               unsigned short* __restrict__ o) {
  int i = blockIdx.x * 256 + threadIdx.x;  // handles 4 elems
  if (i >= NB * NN * NN / 4) return;
  float4 a = *(const float4*)(adj + (size_t)i * 4);
  ushort4 r;
  r.x = f2bf(a.x); r.y = f2bf(a.y); r.z = f2bf(a.z); r.w = f2bf(a.w);
  *(ushort4*)(o + (size_t)i * 4) = r;
}

// ---------------------------------------------------------------------------
// 1) xs = x*(1+0.3*x[..,62]*exp(-x[..,63]/60));  h0 = bf16(xs @ W_gp + b_gp)
// ---------------------------------------------------------------------------
__global__ __launch_bounds__(256) void k_scale_gp(
    const float* __restrict__ x, const float* __restrict__ W,
    const float* __restrict__ bias, unsigned short* __restrict__ out) {
  __shared__ float Ws[64][64];
  __shared__ float xr[16][64];
  __shared__ float sf[16];
  int tid = threadIdx.x;
  int col = tid & 63, rg = tid >> 6;
  int row0 = blockIdx.x * 16;
  for (int i = tid; i < 4096; i += 256) Ws[i >> 6][i & 63] = W[i];
  for (int i = tid; i < 1024; i += 256)
    xr[i >> 6][i & 63] = x[(size_t)row0 * 64 + i];
  __syncthreads();
  if (tid < 16) {
    float a = xr[tid][62] * __expf(-xr[tid][63] * (1.0f / 60.0f));
    sf[tid] = 1.0f + 0.3f * a;
  }
  __syncthreads();
  float bv = bias[col];
  for (int rr = 0; rr < 4; ++rr) {
    int r = rg * 4 + rr;
    float acc = 0.f;
#pragma unroll
    for (int i = 0; i < 64; ++i) acc += xr[r][i] * Ws[i][col];
    out[(size_t)(row0 + r) * 64 + col] = f2bf(acc * sf[r] + bv);
  }
}

// ---------------------------------------------------------------------------
// 2) MFMA graph propagation: h' = relu(adj @ h)  (bf16 in/out, f32 accumulate)
//    LAST: pout = relu(adj@h) + x  (f32)
//    Block: 256 thr = 4 waves, output tile 32 nodes x 64 channels.
// ---------------------------------------------------------------------------
template <bool LAST>
__global__ __launch_bounds__(256) void k_prop_mfma(
    const unsigned short* __restrict__ adjB,   // [NB][800][800] bf16
    const unsigned short* __restrict__ hin,    // [NBS][800][64] bf16
    const float* __restrict__ x,
    unsigned short* __restrict__ hout,         // bf16 (!LAST)
    float* __restrict__ pout) {                // f32  (LAST)
  __shared__ unsigned short As[32][36];   // adj tile [n][k], padded
  __shared__ unsigned short Bs[64][36];   // hT tile  [c][k], padded
  const int tid = threadIdx.x;
  const int bid = blockIdx.x;
  const int bs = bid / 25, mt = bid % 25;
  const int b = bs / NS;
  const int n0 = mt * 32;
  const unsigned short* abase = adjB + (size_t)b * NN * NN + (size_t)n0 * NN;
  const unsigned short* hbase = hin + (size_t)bs * NN * 64;
  const int w = tid >> 6, l = tid & 63;
  const int rb = (w & 1) * 16;   // wave row offset in tile
  const int cb = (w >> 1) * 32;  // wave col offset in tile
  f32x4 acc0 = {0.f, 0.f, 0.f, 0.f}, acc1 = {0.f, 0.f, 0.f, 0.f};
  // staging maps
  const int ar = tid >> 3, ak = (tid & 7) * 4;    // A: 32 rows x 8 b64
  const int bc = tid & 63, bm0 = (tid >> 6) * 4;  // B: 64 cols x 4 m-pairs
  const int k4 = (l >> 4) * 4;
  const int arow = rb + (l & 15);
  const int bcol0 = cb + (l & 15);
  for (int m0 = 0; m0 < NN; m0 += 32) {
    __syncthreads();
    *(s16x4*)&As[ar][ak] =
        *(const s16x4*)(abase + (size_t)ar * NN + m0 + ak);
#pragma unroll
    for (int j = 0; j < 4; ++j) {
      int mp = bm0 + j;
      unsigned lo = hbase[(size_t)(m0 + 2 * mp) * 64 + bc];
      unsigned hi = hbase[(size_t)(m0 + 2 * mp + 1) * 64 + bc];
      *(unsigned*)&Bs[bc][2 * mp] = lo | (hi << 16);
    }
    __syncthreads();
    s16x4 alo = *(const s16x4*)&As[arow][k4];
    s16x4 ahi = *(const s16x4*)&As[arow][k4 + 16];
    s16x8 a = {alo.x, alo.y, alo.z, alo.w, ahi.x, ahi.y, ahi.z, ahi.w};
    s16x4 b0l = *(const s16x4*)&Bs[bcol0][k4];
    s16x4 b0h = *(const s16x4*)&Bs[bcol0][k4 + 16];
    s16x8 bf0 = {b0l.x, b0l.y, b0l.z, b0l.w, b0h.x, b0h.y, b0h.z, b0h.w};
    s16x4 b1l = *(const s16x4*)&Bs[bcol0 + 16][k4];
    s16x4 b1h = *(const s16x4*)&Bs[bcol0 + 16][k4 + 16];
    s16x8 bf1 = {b1l.x, b1l.y, b1l.z, b1l.w, b1h.x, b1h.y, b1h.z, b1h.w};
    acc0 = __builtin_amdgcn_mfma_f32_16x16x32_bf16(a, bf0, acc0, 0, 0, 0);
    acc1 = __builtin_amdgcn_mfma_f32_16x16x32_bf16(a, bf1, acc1, 0, 0, 0);
  }
#pragma unroll
  for (int r = 0; r < 4; ++r) {
    int n = n0 + rb + (l >> 4) * 4 + r;
    int c0 = cb + (l & 15);
    float v0 = fmaxf(acc0[r], 0.f);
    float v1 = fmaxf(acc1[r], 0.f);
    size_t i0 = ((size_t)bs * NN + n) * 64 + c0;
    size_t i1 = i0 + 16;
    if (LAST) {
      pout[i0] = v0 + x[i0];
      pout[i1] = v1 + x[i1];
    } else {
      hout[i0] = f2bf(v0);
      hout[i1] = f2bf(v1);
    }
  }
}

// ---------------------------------------------------------------------------
// 3) fused Q/K/V linear: {Q,K,V} = X@W* + b*
// ---------------------------------------------------------------------------
__global__ __launch_bounds__(256) void k_qkv3(
    const float* __restrict__ X, const float* __restrict__ Wq,
    const float* __restrict__ Wk, const float* __restrict__ Wv,
    const float* __restrict__ bq, const float* __restrict__ bk,
    const float* __restrict__ bv, float* __restrict__ Q, float* __restrict__ K,
    float* __restrict__ V) {
  __shared__ float Wqs[64][64], Wks[64][64], Wvs[64][64];
  __shared__ float xr[16][64];
  int tid = threadIdx.x;
  int col = tid & 63, rg = tid >> 6;
  int row0 = blockIdx.x * 16;
  for (int i = tid; i < 4096; i += 256) {
    Wqs[i >> 6][i & 63] = Wq[i];
    Wks[i >> 6][i & 63] = Wk[i];
    Wvs[i >> 6][i & 63] = Wv[i];
  }
  for (int i = tid; i < 1024; i += 256)
    xr[i >> 6][i & 63] = X[(size_t)row0 * 64 + i];
  __syncthreads();
  float bqv = bq[col], bkv = bk[col], bvv = bv[col];
  for (int rr = 0; rr < 4; ++rr) {
    int r = rg * 4 + rr;
    float aq = bqv, ak = bkv, av = bvv;
#pragma unroll
    for (int i = 0; i < 64; ++i) {
      float xv = xr[r][i];
      aq += xv * Wqs[i][col];
      ak += xv * Wks[i][col];
      av += xv * Wvs[i][col];
    }
    size_t o = (size_t)(row0 + r) * 64 + col;
    Q[o] = aq;
    K[o] = ak;
    V[o] = av;
  }
}

// ---------------------------------------------------------------------------
// 4) spatial attention: one query/thread, K/V via wave-uniform (scalar) loads.
//    No LDS at all. 8-key tiles with block rescale.
// ---------------------------------------------------------------------------
__global__ __launch_bounds__(256) void k_sattn(const float* __restrict__ Q,
                                               const float* __restrict__ K,
                                               const float* __restrict__ V,
                                               float* __restrict__ O) {
  const int bs = blockIdx.x, h = blockIdx.y;
  const int l = blockIdx.z * 256 + threadIdx.x;
  if (l >= NN) return;
  const size_t base = (size_t)bs * NN * 64 + h * DH;
  const float* __restrict__ Kb = K + base;
  const float* __restrict__ Vb = V + base;
  const float* qp = Q + base + (size_t)l * 64;
  float4 q0 = *(const float4*)qp;
  float4 q1 = *(const float4*)(qp + 4);
  const float sc = 0.35355339059327373f;
  q0.x *= sc; q0.y *= sc; q0.z *= sc; q0.w *= sc;
  q1.x *= sc; q1.y *= sc; q1.z *= sc; q1.w *= sc;
  float m = -1e30f, lsum = 0.f;
  float4 o0 = {0, 0, 0, 0}, o1 = {0, 0, 0, 0};
  for (int k0 = 0; k0 < NN; k0 += 8) {
    float s[8];
#pragma unroll
    for (int kk = 0; kk < 8; ++kk) {
      const float* kp = Kb + (size_t)(k0 + kk) * 64;
      float4 ka = *(const float4*)kp;
      float4 kb = *(const float4*)(kp + 4);
      s[kk] = q0.x * ka.x + q0.y * ka.y + q0.z * ka.z + q0.w * ka.w +
              q1.x * kb.x + q1.y * kb.y + q1.z * kb.z + q1.w * kb.w;
    }
    float tm = fmaxf(fmaxf(fmaxf(s[0], s[1]), fmaxf(s[2], s[3])),
                     fmaxf(fmaxf(s[4], s[5]), fmaxf(s[6], s[7])));
    float mn = fmaxf(m, tm);
    float corr = __expf(m - mn);
    lsum *= corr;
    o0.x *= corr; o0.y *= corr; o0.z *= corr; o0.w *= corr;
    o1.x *= corr; o1.y *= corr; o1.z *= corr; o1.w *= corr;
#pragma unroll
    for (int kk = 0; kk < 8; ++kk) {
      float p = __expf(s[kk] - mn);
      lsum += p;
      const float* vp = Vb + (size_t)(k0 + kk) * 64;
      float4 va = *(const float4*)vp;
      float4 vb = *(const float4*)(vp + 4);
      o0.x += p * va.x; o0.y += p * va.y; o0.z += p * va.z; o0.w += p * va.w;
      o1.x += p * vb.x; o1.y += p * vb.y; o1.z += p * vb.z; o1.w += p * vb.w;
    }
    m = mn;
  }
  float inv = 1.f / lsum;
  float* op = O + base + (size_t)l * 64;
  float4 r0 = {o0.x * inv, o0.y * inv, o0.z * inv, o0.w * inv};
  float4 r1 = {o1.x * inv, o1.y * inv, o1.z * inv, o1.w * inv};
  *(float4*)op = r0;
  *(float4*)(op + 4) = r1;
}

// ---------------------------------------------------------------------------
// 5) y = LN(X@W + b + res; g, be)   (wave per row)
// ---------------------------------------------------------------------------
__global__ __launch_bounds__(256) void k_projln(
    const float* __restrict__ X, const float* __restrict__ W,
    const float* __restrict__ bias, const float* __restrict__ res,
    const float* __restrict__ g, const float* __restrict__ be,
    float* __restrict__ out) {
  __shared__ float Ws[64][64];
  int tid = threadIdx.x;
  int lane = tid & 63, w = tid >> 6;
  for (int i = tid; i < 4096; i += 256) Ws[i >> 6][i & 63] = W[i];
  __syncthreads();
  int row = blockIdx.x * 4 + w;
  float xv = X[(size_t)row * 64 + lane];
  float acc = bias[lane];
#pragma unroll
  for (int i = 0; i < 64; ++i) acc += __shfl(xv, i, 64) * Ws[i][lane];
  acc += res[(size_t)row * 64 + lane];
  float s = acc;
#pragma unroll
  for (int off = 32; off; off >>= 1) s += __shfl_xor(s, off, 64);
  float mean = s * (1.f / 64.f);
  float d = acc - mean;
  float v = d * d;
#pragma unroll
  for (int off = 32; off; off >>= 1) v += __shfl_xor(v, off, 64);
  float rstd = rsqrtf(v * (1.f / 64.f) + 1e-5f);
  out[(size_t)row * 64 + lane] = d * rstd * g[lane] + be[lane];
}

// ---------------------------------------------------------------------------
// 6) temporal attention: one block per (b,n), L = 12
// ---------------------------------------------------------------------------
__global__ __launch_bounds__(256) void k_tattn(const float* __restrict__ Q,
                                               const float* __restrict__ K,
                                               const float* __restrict__ V,
                                               float* __restrict__ O) {
  int b = blockIdx.x / NN, n = blockIdx.x % NN;
  __shared__ float Qs[12][64], Ks[12][64], Vs[12][64];
  int tid = threadIdx.x;
  for (int i = tid; i < 12 * 64; i += 256) {
    int s = i >> 6, c = i & 63;
    size_t idx = (((size_t)b * NS + s) * NN + n) * 64 + c;
    Qs[s][c] = Q[idx];
    Ks[s][c] = K[idx];
    Vs[s][c] = V[idx];
  }
  __syncthreads();
  for (int wi = tid; wi < 12 * 64; wi += 256) {
    int l = wi >> 6, c = wi & 63;
    int h8 = c & 56;
    float sc[12];
    float mx = -1e30f;
#pragma unroll
    for (int m = 0; m < 12; ++m) {
      float s = 0.f;
#pragma unroll
      for (int d = 0; d < 8; ++d) s += Qs[l][h8 + d] * Ks[m][h8 + d];
      s *= 0.35355339059327373f;
      sc[m] = s;
      mx = fmaxf(mx, s);
    }
    float sum = 0.f;
#pragma unroll
    for (int m = 0; m < 12; ++m) {
      sc[m] = __expf(sc[m] - mx);
      sum += sc[m];
    }
    float inv = 1.f / sum;
    float o = 0.f;
#pragma unroll
    for (int m = 0; m < 12; ++m) o += sc[m] * Vs[m][c];
    size_t idx = (((size_t)b * NS + l) * NN + n) * 64 + c;
    O[idx] = o * inv;
  }
}

// ---------------------------------------------------------------------------
// 7) plain LN (wave per row)
// ---------------------------------------------------------------------------
__global__ __launch_bounds__(256) void k_ln(const float* __restrict__ X,
                                            const float* __restrict__ g,
                                            const float* __restrict__ be,
                                            float* __restrict__ out) {
  int tid = threadIdx.x;
  int lane = tid & 63, w = tid >> 6;
  int row = blockIdx.x * 4 + w;
  float acc = X[(size_t)row * 64 + lane];
  float s = acc;
#pragma unroll
  for (int off = 32; off; off >>= 1) s += __shfl_xor(s, off, 64);
  float mean = s * (1.f / 64.f);
  float d = acc - mean;
  float v = d * d;
#pragma unroll
  for (int off = 32; off; off >>= 1) v += __shfl_xor(v, off, 64);
  float rstd = rsqrtf(v * (1.f / 64.f) + 1e-5f);
  out[(size_t)row * 64 + lane] = d * rstd * g[lane] + be[lane];
}

// ---------------------------------------------------------------------------
// 8) FFN layer 1: hid = relu(X@W1 + b1), W1 is 64x256
// ---------------------------------------------------------------------------
__global__ __launch_bounds__(256) void k_ffn1(const float* __restrict__ X,
                                              const float* __restrict__ W1,
                                              const float* __restrict__ b1,
                                              float* __restrict__ Hid) {
  __shared__ float Ws[64][256];  // 64 KB
  int tid = threadIdx.x;
  for (int i = tid; i < 64 * 256; i += 256) Ws[i >> 8][i & 255] = W1[i];
  __syncthreads();
  int row0 = blockIdx.x * 16;
  float bv = b1[tid];
  for (int r = 0; r < 16; ++r) {
    const float* xr = X + (size_t)(row0 + r) * 64;
    float acc = bv;
#pragma unroll
    for (int i = 0; i < 64; ++i) acc += xr[i] * Ws[i][tid];
    Hid[(size_t)(row0 + r) * 256 + tid] = fmaxf(acc, 0.f);
  }
}

// ---------------------------------------------------------------------------
// 9) FFN layer 2 + residual + final LN:  out = LN(hid@W2 + b2 + res; g2, be2)
// ---------------------------------------------------------------------------
__global__ __launch_bounds__(256) void k_ffn2ln(
    const float* __restrict__ Hd, const float* __restrict__ W2,
    const float* __restrict__ b2, const float* __restrict__ res,
    const float* __restrict__ g, const float* __restrict__ be,
    float* __restrict__ out) {
  __shared__ float Ws[256][64];  // 64 KB
  int tid = threadIdx.x;
  int lane = tid & 63, w = tid >> 6;
  for (int i = tid; i < 256 * 64; i += 256) Ws[i >> 6][i & 63] = W2[i];
  __syncthreads();
  int row = blockIdx.x * 4 + w;
  const float* hr = Hd + (size_t)row * 256;
  float acc = b2[lane] + res[(size_t)row * 64 + lane];
#pragma unroll
  for (int c = 0; c < 4; ++c) {
    float hv = hr[c * 64 + lane];
#pragma unroll
    for (int i = 0; i < 64; ++i) acc += __shfl(hv, i, 64) * Ws[c * 64 + i][lane];
  }
  float s = acc;
#pragma unroll
  for (int off = 32; off; off >>= 1) s += __shfl_xor(s, off, 64);
  float mean = s * (1.f / 64.f);
  float d = acc - mean;
  float v = d * d;
#pragma unroll
  for (int off = 32; off; off >>= 1) v += __shfl_xor(v, off, 64);
  float rstd = rsqrtf(v * (1.f / 64.f) + 1e-5f);
  out[(size_t)row * 64 + lane] = d * rstd * g[lane] + be[lane];
}

// ---------------------------------------------------------------------------
extern "C" void kernel_launch(void* const* d_in, const int* in_sizes, int n_in,
                              void* d_out, int out_size, void* d_ws,
                              size_t ws_size, hipStream_t stream) {
  const float* x = (const float*)d_in[0];
  const float* adj = (const float*)d_in[1];
  const float* W_gp = (const float*)d_in[2];
  const float* b_gp = (const float*)d_in[3];
  const float* Wq_s = (const float*)d_in[4];
  const float* Wk_s = (const float*)d_in[5];
  const float* Wv_s = (const float*)d_in[6];
  const float* Wo_s = (const float*)d_in[7];
  const float* bq_s = (const float*)d_in[8];
  const float* bk_s = (const float*)d_in[9];
  const float* bv_s = (const float*)d_in[10];
  const float* bo_s = (const float*)d_in[11];
  const float* g_s = (const float*)d_in[12];
  const float* be_s = (const float*)d_in[13];
  const float* Wq_t = (const float*)d_in[14];
  const float* Wk_t = (const float*)d_in[15];
  const float* Wv_t = (const float*)d_in[16];
  const float* Wo_t = (const float*)d_in[17];
  const float* bq_t = (const float*)d_in[18];
  const float* bk_t = (const float*)d_in[19];
  const float* bv_t = (const float*)d_in[20];
  const float* bo_t = (const float*)d_in[21];
  const float* g_t = (const float*)d_in[22];
  const float* be_t = (const float*)d_in[23];
  const float* W1 = (const float*)d_in[24];
  const float* b1 = (const float*)d_in[25];
  const float* W2 = (const float*)d_in[26];
  const float* b2 = (const float*)d_in[27];
  const float* g1 = (const float*)d_in[28];
  const float* be1 = (const float*)d_in[29];
  const float* g2 = (const float*)d_in[30];
  const float* be2 = (const float*)d_in[31];
  float* out = (float*)d_out;

  float* ws = (float*)d_ws;
  const size_t U = (size_t)NR * 64;  // 1,228,800 floats
  float* A = ws + 0 * U;
  float* Bb = ws + 1 * U;
  float* C = ws + 2 * U;
  float* D = ws + 3 * U;
  float* P = ws + 4 * U;
  float* HID = ws + 5 * U;                              // NR x 256 = 4U
  unsigned short* HB0 = (unsigned short*)(ws + 9 * U);  // bf16, 0.5U
  unsigned short* HB1 = (unsigned short*)(ws + 9 * U + U / 2);
  unsigned short* ADJB = (unsigned short*)(ws + 10 * U);  // bf16, ~0.52U

  dim3 blk(256);
  // 0) adj -> bf16
  k_adjbf<<<(NB * NN * NN / 4 + 255) / 256, blk, 0, stream>>>(adj, ADJB);
  // 1) scale + graph linear -> HB0 (bf16)
  k_scale_gp<<<NR / 16, blk, 0, stream>>>(x, W_gp, b_gp, HB0);
  // 2) 3 MFMA propagation steps; residual fused into last -> P (f32)
  k_prop_mfma<false><<<NBS * 25, blk, 0, stream>>>(ADJB, HB0, x, HB1, P);
  k_prop_mfma<false><<<NBS * 25, blk, 0, stream>>>(ADJB, HB1, x, HB0, P);
  k_prop_mfma<true><<<NBS * 25, blk, 0, stream>>>(ADJB, HB0, x, HB1, P);
  // 3) spatial QKV -> A,Bb,C ; attn -> D ; proj+LN -> A (res = P)
  k_qkv3<<<NR / 16, blk, 0, stream>>>(P, Wq_s, Wk_s, Wv_s, bq_s, bk_s, bv_s, A,
                                      Bb, C);
  k_sattn<<<dim3(NBS, HEADS, 4), blk, 0, stream>>>(A, Bb, C, D);
  k_projln<<<NR / 4, blk, 0, stream>>>(D, Wo_s, bo_s, P, g_s, be_s, A);
  // 4) temporal QKV -> Bb,C,D ; attn -> P ; proj+LN -> Bb (res = A)
  k_qkv3<<<NR / 16, blk, 0, stream>>>(A, Wq_t, Wk_t, Wv_t, bq_t, bk_t, bv_t, Bb,
                                      C, D);
  k_tattn<<<NB * NN, blk, 0, stream>>>(Bb, C, D, P);
  k_projln<<<NR / 4, blk, 0, stream>>>(P, Wo_t, bo_t, A, g_t, be_t, Bb);
  // 5) FFN: LN1 -> C ; hid -> HID ; W2 + residual + final LN -> out
  k_ln<<<NR / 4, blk, 0, stream>>>(Bb, g1, be1, C);
  k_ffn1<<<NR / 16, blk, 0, stream>>>(C, W1, b1, HID);
  k_ffn2ln<<<NR / 4, blk, 0, stream>>>(HID, W2, b2, Bb, g2, be2, out);
}

// Round 3
// 441.396 us; speedup vs baseline: 1.5101x; 1.0539x over previous
//
#include <hip/hip_runtime.h>
#include <hip/hip_bf16.h>

#define NB 2
#define NS 12
#define NN 800
#define NH 64      // hidden
#define HEADS 8
#define DH 8
#define NBS (NB*NS)        // 24
#define NR (NB*NS*NN)      // 19200 rows
#define KSPLIT 4
#define NQ (NR*HEADS)      // 153600 queries

typedef __attribute__((ext_vector_type(4))) float f32x4;
typedef __attribute__((ext_vector_type(4))) short s16x4;
typedef __attribute__((ext_vector_type(8))) short s16x8;

static __device__ __forceinline__ unsigned short f2bf(float f) {
  union { float f; unsigned u; } v; v.f = f;
  unsigned r = (v.u + 0x7FFFu + ((v.u >> 16) & 1u)) >> 16;
  return (unsigned short)r;
}

// ---------------------------------------------------------------------------
// 0a) adj f32 -> bf16
// ---------------------------------------------------------------------------
__global__ __launch_bounds__(256) void k_adjbf(const float* __restrict__ adj,
                                               unsigned short* __restrict__ o) {
  int i = blockIdx.x * 256 + threadIdx.x;  // handles 4 elems
  if (i >= NB * NN * NN / 4) return;
  float4 a = *(const float4*)(adj + (size_t)i * 4);
  ushort4 r;
  r.x = f2bf(a.x); r.y = f2bf(a.y); r.z = f2bf(a.z); r.w = f2bf(a.w);
  *(ushort4*)(o + (size_t)i * 4) = r;
}

// ---------------------------------------------------------------------------
// 0b) 6 weight matrices f32 -> bf16 (Wq_s,Wk_s,Wv_s,Wq_t,Wk_t,Wv_t)
// ---------------------------------------------------------------------------
__global__ __launch_bounds__(256) void k_w2bf(
    const float* __restrict__ w0, const float* __restrict__ w1,
    const float* __restrict__ w2, const float* __restrict__ w3,
    const float* __restrict__ w4, const float* __restrict__ w5,
    unsigned short* __restrict__ out) {
  const float* ws[6] = {w0, w1, w2, w3, w4, w5};
  int y = blockIdx.y;
  int i = blockIdx.x * 256 + threadIdx.x;
  if (i < 4096) out[y * 4096 + i] = f2bf(ws[y][i]);
}

// ---------------------------------------------------------------------------
// 1) xs = x*(1+0.3*x[..,62]*exp(-x[..,63]/60));  h0 = bf16(xs @ W_gp + b_gp)
// ---------------------------------------------------------------------------
__global__ __launch_bounds__(256) void k_scale_gp(
    const float* __restrict__ x, const float* __restrict__ W,
    const float* __restrict__ bias, unsigned short* __restrict__ out) {
  __shared__ float Ws[64][64];
  __shared__ float xr[16][64];
  __shared__ float sf[16];
  int tid = threadIdx.x;
  int col = tid & 63, rg = tid >> 6;
  int row0 = blockIdx.x * 16;
  for (int i = tid; i < 4096; i += 256) Ws[i >> 6][i & 63] = W[i];
  for (int i = tid; i < 1024; i += 256)
    xr[i >> 6][i & 63] = x[(size_t)row0 * 64 + i];
  __syncthreads();
  if (tid < 16) {
    float a = xr[tid][62] * __expf(-xr[tid][63] * (1.0f / 60.0f));
    sf[tid] = 1.0f + 0.3f * a;
  }
  __syncthreads();
  float bv = bias[col];
  for (int rr = 0; rr < 4; ++rr) {
    int r = rg * 4 + rr;
    float acc = 0.f;
#pragma unroll
    for (int i = 0; i < 64; ++i) acc += xr[r][i] * Ws[i][col];
    out[(size_t)(row0 + r) * 64 + col] = f2bf(acc * sf[r] + bv);
  }
}

// ---------------------------------------------------------------------------
// 2) MFMA graph propagation: h' = relu(adj @ h)
//    LAST: pout = relu(adj@h) + x (f32)  AND  pbout = bf16(pout)
// ---------------------------------------------------------------------------
template <bool LAST>
__global__ __launch_bounds__(256) void k_prop_mfma(
    const unsigned short* __restrict__ adjB,   // [NB][800][800] bf16
    const unsigned short* __restrict__ hin,    // [NBS][800][64] bf16
    const float* __restrict__ x,
    unsigned short* __restrict__ hout,         // bf16 (!LAST)
    float* __restrict__ pout,                  // f32  (LAST)
    unsigned short* __restrict__ pbout) {      // bf16 (LAST)
  __shared__ unsigned short As[32][36];
  __shared__ unsigned short Bs[64][36];
  const int tid = threadIdx.x;
  const int bid = blockIdx.x;
  const int bs = bid / 25, mt = bid % 25;
  const int b = bs / NS;
  const int n0 = mt * 32;
  const unsigned short* abase = adjB + (size_t)b * NN * NN + (size_t)n0 * NN;
  const unsigned short* hbase = hin + (size_t)bs * NN * 64;
  const int w = tid >> 6, l = tid & 63;
  const int rb = (w & 1) * 16;
  const int cb = (w >> 1) * 32;
  f32x4 acc0 = {0.f, 0.f, 0.f, 0.f}, acc1 = {0.f, 0.f, 0.f, 0.f};
  const int ar = tid >> 3, ak = (tid & 7) * 4;
  const int bc = tid & 63, bm0 = (tid >> 6) * 4;
  const int k4 = (l >> 4) * 4;
  const int arow = rb + (l & 15);
  const int bcol0 = cb + (l & 15);
  for (int m0 = 0; m0 < NN; m0 += 32) {
    __syncthreads();
    *(s16x4*)&As[ar][ak] =
        *(const s16x4*)(abase + (size_t)ar * NN + m0 + ak);
#pragma unroll
    for (int j = 0; j < 4; ++j) {
      int mp = bm0 + j;
      unsigned lo = hbase[(size_t)(m0 + 2 * mp) * 64 + bc];
      unsigned hi = hbase[(size_t)(m0 + 2 * mp + 1) * 64 + bc];
      *(unsigned*)&Bs[bc][2 * mp] = lo | (hi << 16);
    }
    __syncthreads();
    s16x4 alo = *(const s16x4*)&As[arow][k4];
    s16x4 ahi = *(const s16x4*)&As[arow][k4 + 16];
    s16x8 a = {alo.x, alo.y, alo.z, alo.w, ahi.x, ahi.y, ahi.z, ahi.w};
    s16x4 b0l = *(const s16x4*)&Bs[bcol0][k4];
    s16x4 b0h = *(const s16x4*)&Bs[bcol0][k4 + 16];
    s16x8 bf0 = {b0l.x, b0l.y, b0l.z, b0l.w, b0h.x, b0h.y, b0h.z, b0h.w};
    s16x4 b1l = *(const s16x4*)&Bs[bcol0 + 16][k4];
    s16x4 b1h = *(const s16x4*)&Bs[bcol0 + 16][k4 + 16];
    s16x8 bf1 = {b1l.x, b1l.y, b1l.z, b1l.w, b1h.x, b1h.y, b1h.z, b1h.w};
    acc0 = __builtin_amdgcn_mfma_f32_16x16x32_bf16(a, bf0, acc0, 0, 0, 0);
    acc1 = __builtin_amdgcn_mfma_f32_16x16x32_bf16(a, bf1, acc1, 0, 0, 0);
  }
#pragma unroll
  for (int r = 0; r < 4; ++r) {
    int n = n0 + rb + (l >> 4) * 4 + r;
    int c0 = cb + (l & 15);
    float v0 = fmaxf(acc0[r], 0.f);
    float v1 = fmaxf(acc1[r], 0.f);
    size_t i0 = ((size_t)bs * NN + n) * 64 + c0;
    size_t i1 = i0 + 16;
    if (LAST) {
      float p0 = v0 + x[i0], p1 = v1 + x[i1];
      pout[i0] = p0;
      pout[i1] = p1;
      pbout[i0] = f2bf(p0);
      pbout[i1] = f2bf(p1);
    } else {
      hout[i0] = f2bf(v0);
      hout[i1] = f2bf(v1);
    }
  }
}

// ---------------------------------------------------------------------------
// 3) MFMA fused QKV: {Q,K,V} = Xb @ Wb{q,k,v} + b{q,k,v}   (f32 out)
//    Block: 32 rows x 64 cols, 4 waves, K=64 in 2 steps.
// ---------------------------------------------------------------------------
__global__ __launch_bounds__(256) void k_qkv_mfma(
    const unsigned short* __restrict__ Xb,   // [NR][64] bf16
    const unsigned short* __restrict__ Wq,   // [64][64] bf16
    const unsigned short* __restrict__ Wk,
    const unsigned short* __restrict__ Wv,
    const float* __restrict__ bq, const float* __restrict__ bk,
    const float* __restrict__ bv,
    float* __restrict__ Q, float* __restrict__ K, float* __restrict__ V) {
  __shared__ unsigned short As[32][36];
  __shared__ unsigned short Bs[3][64][36];
  const int tid = threadIdx.x;
  const int r0 = blockIdx.x * 32;
  const int w = tid >> 6, l = tid & 63;
  const int rb = (w & 1) * 16;
  const int cb = (w >> 1) * 32;
  f32x4 acc[3][2];
#pragma unroll
  for (int i = 0; i < 3; ++i)
#pragma unroll
    for (int j = 0; j < 2; ++j) acc[i][j] = (f32x4){0.f, 0.f, 0.f, 0.f};
  const unsigned short* Wm[3] = {Wq, Wk, Wv};
  const int ar = tid >> 3, ak = (tid & 7) * 4;
  const int bc = tid & 63, bm0 = (tid >> 6) * 4;
  const int k4 = (l >> 4) * 4;
  const int arow = rb + (l & 15);
  const int bcol0 = cb + (l & 15);
  for (int k0 = 0; k0 < 64; k0 += 32) {
    __syncthreads();
    *(s16x4*)&As[ar][ak] =
        *(const s16x4*)(Xb + (size_t)(r0 + ar) * 64 + k0 + ak);
#pragma unroll
    for (int wm = 0; wm < 3; ++wm) {
#pragma unroll
      for (int j = 0; j < 4; ++j) {
        int mp = bm0 + j;
        unsigned lo = Wm[wm][(size_t)(k0 + 2 * mp) * 64 + bc];
        unsigned hi = Wm[wm][(size_t)(k0 + 2 * mp + 1) * 64 + bc];
        *(unsigned*)&Bs[wm][bc][2 * mp] = lo | (hi << 16);
      }
    }
    __syncthreads();
    s16x4 alo = *(const s16x4*)&As[arow][k4];
    s16x4 ahi = *(const s16x4*)&As[arow][k4 + 16];
    s16x8 a = {alo.x, alo.y, alo.z, alo.w, ahi.x, ahi.y, ahi.z, ahi.w};
#pragma unroll
    for (int wm = 0; wm < 3; ++wm) {
      s16x4 b0l = *(const s16x4*)&Bs[wm][bcol0][k4];
      s16x4 b0h = *(const s16x4*)&Bs[wm][bcol0][k4 + 16];
      s16x8 bf0 = {b0l.x, b0l.y, b0l.z, b0l.w, b0h.x, b0h.y, b0h.z, b0h.w};
      s16x4 b1l = *(const s16x4*)&Bs[wm][bcol0 + 16][k4];
      s16x4 b1h = *(const s16x4*)&Bs[wm][bcol0 + 16][k4 + 16];
      s16x8 bf1 = {b1l.x, b1l.y, b1l.z, b1l.w, b1h.x, b1h.y, b1h.z, b1h.w};
      acc[wm][0] = __builtin_amdgcn_mfma_f32_16x16x32_bf16(a, bf0, acc[wm][0], 0, 0, 0);
      acc[wm][1] = __builtin_amdgcn_mfma_f32_16x16x32_bf16(a, bf1, acc[wm][1], 0, 0, 0);
    }
  }
  float* Om[3] = {Q, K, V};
  const float* bm[3] = {bq, bk, bv};
  const int c0 = cb + (l & 15);
#pragma unroll
  for (int wm = 0; wm < 3; ++wm) {
    float b0 = bm[wm][c0], b1 = bm[wm][c0 + 16];
#pragma unroll
    for (int r = 0; r < 4; ++r) {
      int row = r0 + rb + (l >> 4) * 4 + r;
      Om[wm][(size_t)row * 64 + c0] = acc[wm][0][r] + b0;
      Om[wm][(size_t)row * 64 + c0 + 16] = acc[wm][1][r] + b1;
    }
  }
}

// ---------------------------------------------------------------------------
// 4a) spatial attention partials: 1 wave/block, 4 queries/thread, key-split.
//     Partials: m, l, unnormalized o[8] per (query, split).
// ---------------------------------------------------------------------------
__global__ __launch_bounds__(64) void k_sattn_part(
    const float* __restrict__ Q, const float* __restrict__ K,
    const float* __restrict__ V, float* __restrict__ Pm,
    float* __restrict__ Pl, float* __restrict__ Po) {
  const int bs = blockIdx.x, h = blockIdx.y;
  const int qc = blockIdx.z / KSPLIT, sp = blockIdx.z % KSPLIT;
  const int lane = threadIdx.x;
  const size_t base = (size_t)bs * NN * 64 + h * DH;
  const float* __restrict__ Kb = K + base;
  const float* __restrict__ Vb = V + base;
  const float sc = 0.35355339059327373f;
  int lq[4];
  float4 q0[4], q1[4];
  float m[4], lsum[4];
  float4 o0[4], o1[4];
#pragma unroll
  for (int qq = 0; qq < 4; ++qq) {
    int l = qc * 256 + qq * 64 + lane;
    lq[qq] = l;
    int lc = l < NN ? l : 0;
    const float* qp = Q + base + (size_t)lc * 64;
    float4 a = *(const float4*)qp;
    float4 b = *(const float4*)(qp + 4);
    a.x *= sc; a.y *= sc; a.z *= sc; a.w *= sc;
    b.x *= sc; b.y *= sc; b.z *= sc; b.w *= sc;
    q0[qq] = a; q1[qq] = b;
    m[qq] = -1e30f; lsum[qq] = 0.f;
    o0[qq] = (float4){0, 0, 0, 0}; o1[qq] = (float4){0, 0, 0, 0};
  }
  const int kbeg = sp * (NN / KSPLIT);
  const int kend = kbeg + NN / KSPLIT;
  for (int k0 = kbeg; k0 < kend; k0 += 4) {
    float4 kr0[4], kr1[4], vr0[4], vr1[4];
#pragma unroll
    for (int kk = 0; kk < 4; ++kk) {
      const float* kp = Kb + (size_t)(k0 + kk) * 64;
      kr0[kk] = *(const float4*)kp;
      kr1[kk] = *(const float4*)(kp + 4);
      const float* vp = Vb + (size_t)(k0 + kk) * 64;
      vr0[kk] = *(const float4*)vp;
      vr1[kk] = *(const float4*)(vp + 4);
    }
#pragma unroll
    for (int qq = 0; qq < 4; ++qq) {
      float s[4];
#pragma unroll
      for (int kk = 0; kk < 4; ++kk) {
        s[kk] = q0[qq].x * kr0[kk].x + q0[qq].y * kr0[kk].y +
                q0[qq].z * kr0[kk].z + q0[qq].w * kr0[kk].w +
                q1[qq].x * kr1[kk].x + q1[qq].y * kr1[kk].y +
                q1[qq].z * kr1[kk].z + q1[qq].w * kr1[kk].w;
      }
      float tm = fmaxf(fmaxf(s[0], s[1]), fmaxf(s[2], s[3]));
      float mn = fmaxf(m[qq], tm);
      float corr = __expf(m[qq] - mn);
      m[qq] = mn;
      float ls = lsum[qq] * corr;
      float4 a0 = o0[qq], a1 = o1[qq];
      a0.x *= corr; a0.y *= corr; a0.z *= corr; a0.w *= corr;
      a1.x *= corr; a1.y *= corr; a1.z *= corr; a1.w *= corr;
#pragma unroll
      for (int kk = 0; kk < 4; ++kk) {
        float p = __expf(s[kk] - mn);
        ls += p;
        a0.x += p * vr0[kk].x; a0.y += p * vr0[kk].y;
        a0.z += p * vr0[kk].z; a0.w += p * vr0[kk].w;
        a1.x += p * vr1[kk].x; a1.y += p * vr1[kk].y;
        a1.z += p * vr1[kk].z; a1.w += p * vr1[kk].w;
      }
      lsum[qq] = ls;
      o0[qq] = a0; o1[qq] = a1;
    }
  }
#pragma unroll
  for (int qq = 0; qq < 4; ++qq) {
    if (lq[qq] >= NN) continue;
    int qg = (bs * HEADS + h) * NN + lq[qq];
    int pi = sp * NQ + qg;
    Pm[pi] = m[qq];
    Pl[pi] = lsum[qq];
    float* po = Po + (size_t)pi * 8;
    *(float4*)po = o0[qq];
    *(float4*)(po + 4) = o1[qq];
  }
}

// ---------------------------------------------------------------------------
// 4b) combine partials -> O
// ---------------------------------------------------------------------------
__global__ __launch_bounds__(256) void k_sattn_comb(
    const float* __restrict__ Pm, const float* __restrict__ Pl,
    const float* __restrict__ Po, float* __restrict__ O) {
  int qg = blockIdx.x * 256 + threadIdx.x;
  if (qg >= NQ) return;
  float mv[KSPLIT];
  float M = -1e30f;
#pragma unroll
  for (int sp = 0; sp < KSPLIT; ++sp) {
    mv[sp] = Pm[sp * NQ + qg];
    M = fmaxf(M, mv[sp]);
  }
  float L = 0.f;
  float4 a0 = {0, 0, 0, 0}, a1 = {0, 0, 0, 0};
#pragma unroll
  for (int sp = 0; sp < KSPLIT; ++sp) {
    float wgt = __expf(mv[sp] - M);
    L += wgt * Pl[sp * NQ + qg];
    const float* po = Po + ((size_t)sp * NQ + qg) * 8;
    float4 b0 = *(const float4*)po;
    float4 b1 = *(const float4*)(po + 4);
    a0.x += wgt * b0.x; a0.y += wgt * b0.y; a0.z += wgt * b0.z; a0.w += wgt * b0.w;
    a1.x += wgt * b1.x; a1.y += wgt * b1.y; a1.z += wgt * b1.z; a1.w += wgt * b1.w;
  }
  float inv = 1.f / L;
  int bs = qg / (HEADS * NN);
  int rem = qg % (HEADS * NN);
  int h = rem / NN, l = rem % NN;
  float* op = O + ((size_t)bs * NN + l) * 64 + h * DH;
  float4 r0 = {a0.x * inv, a0.y * inv, a0.z * inv, a0.w * inv};
  float4 r1 = {a1.x * inv, a1.y * inv, a1.z * inv, a1.w * inv};
  *(float4*)op = r0;
  *(float4*)(op + 4) = r1;
}

// ---------------------------------------------------------------------------
// 5) y = LN(X@W + b + res; g, be)  (wave per row), optional bf16 copy out
// ---------------------------------------------------------------------------
__global__ __launch_bounds__(256) void k_projln(
    const float* __restrict__ X, const float* __restrict__ W,
    const float* __restrict__ bias, const float* __restrict__ res,
    const float* __restrict__ g, const float* __restrict__ be,
    float* __restrict__ out, unsigned short* __restrict__ bfout) {
  __shared__ float Ws[64][64];
  int tid = threadIdx.x;
  int lane = tid & 63, w = tid >> 6;
  for (int i = tid; i < 4096; i += 256) Ws[i >> 6][i & 63] = W[i];
  __syncthreads();
  int row = blockIdx.x * 4 + w;
  float xv = X[(size_t)row * 64 + lane];
  float acc = bias[lane];
#pragma unroll
  for (int i = 0; i < 64; ++i) acc += __shfl(xv, i, 64) * Ws[i][lane];
  acc += res[(size_t)row * 64 + lane];
  float s = acc;
#pragma unroll
  for (int off = 32; off; off >>= 1) s += __shfl_xor(s, off, 64);
  float mean = s * (1.f / 64.f);
  float d = acc - mean;
  float v = d * d;
#pragma unroll
  for (int off = 32; off; off >>= 1) v += __shfl_xor(v, off, 64);
  float rstd = rsqrtf(v * (1.f / 64.f) + 1e-5f);
  float r = d * rstd * g[lane] + be[lane];
  out[(size_t)row * 64 + lane] = r;
  if (bfout) bfout[(size_t)row * 64 + lane] = f2bf(r);
}

// ---------------------------------------------------------------------------
// 6) temporal attention: one block per (b,n), L = 12
// ---------------------------------------------------------------------------
__global__ __launch_bounds__(256) void k_tattn(const float* __restrict__ Q,
                                               const float* __restrict__ K,
                                               const float* __restrict__ V,
                                               float* __restrict__ O) {
  int b = blockIdx.x / NN, n = blockIdx.x % NN;
  __shared__ float Qs[12][64], Ks[12][64], Vs[12][64];
  int tid = threadIdx.x;
  for (int i = tid; i < 12 * 64; i += 256) {
    int s = i >> 6, c = i & 63;
    size_t idx = (((size_t)b * NS + s) * NN + n) * 64 + c;
    Qs[s][c] = Q[idx];
    Ks[s][c] = K[idx];
    Vs[s][c] = V[idx];
  }
  __syncthreads();
  for (int wi = tid; wi < 12 * 64; wi += 256) {
    int l = wi >> 6, c = wi & 63;
    int h8 = c & 56;
    float sc[12];
    float mx = -1e30f;
#pragma unroll
    for (int m = 0; m < 12; ++m) {
      float s = 0.f;
#pragma unroll
      for (int d = 0; d < 8; ++d) s += Qs[l][h8 + d] * Ks[m][h8 + d];
      s *= 0.35355339059327373f;
      sc[m] = s;
      mx = fmaxf(mx, s);
    }
    float sum = 0.f;
#pragma unroll
    for (int m = 0; m < 12; ++m) {
      sc[m] = __expf(sc[m] - mx);
      sum += sc[m];
    }
    float inv = 1.f / sum;
    float o = 0.f;
#pragma unroll
    for (int m = 0; m < 12; ++m) o += sc[m] * Vs[m][c];
    size_t idx = (((size_t)b * NS + l) * NN + n) * 64 + c;
    O[idx] = o * inv;
  }
}

// ---------------------------------------------------------------------------
// 7) plain LN (wave per row)
// ---------------------------------------------------------------------------
__global__ __launch_bounds__(256) void k_ln(const float* __restrict__ X,
                                            const float* __restrict__ g,
                                            const float* __restrict__ be,
                                            float* __restrict__ out) {
  int tid = threadIdx.x;
  int lane = tid & 63, w = tid >> 6;
  int row = blockIdx.x * 4 + w;
  float acc = X[(size_t)row * 64 + lane];
  float s = acc;
#pragma unroll
  for (int off = 32; off; off >>= 1) s += __shfl_xor(s, off, 64);
  float mean = s * (1.f / 64.f);
  float d = acc - mean;
  float v = d * d;
#pragma unroll
  for (int off = 32; off; off >>= 1) v += __shfl_xor(v, off, 64);
  float rstd = rsqrtf(v * (1.f / 64.f) + 1e-5f);
  out[(size_t)row * 64 + lane] = d * rstd * g[lane] + be[lane];
}

// ---------------------------------------------------------------------------
// 8) FFN layer 1: hid = relu(X@W1 + b1), W1 is 64x256
// ---------------------------------------------------------------------------
__global__ __launch_bounds__(256) void k_ffn1(const float* __restrict__ X,
                                              const float* __restrict__ W1,
                                              const float* __restrict__ b1,
                                              float* __restrict__ Hid) {
  __shared__ float Ws[64][256];  // 64 KB
  int tid = threadIdx.x;
  for (int i = tid; i < 64 * 256; i += 256) Ws[i >> 8][i & 255] = W1[i];
  __syncthreads();
  int row0 = blockIdx.x * 16;
  float bv = b1[tid];
  for (int r = 0; r < 16; ++r) {
    const float* xr = X + (size_t)(row0 + r) * 64;
    float acc = bv;
#pragma unroll
    for (int i = 0; i < 64; ++i) acc += xr[i] * Ws[i][tid];
    Hid[(size_t)(row0 + r) * 256 + tid] = fmaxf(acc, 0.f);
  }
}

// ---------------------------------------------------------------------------
// 9) FFN layer 2 + residual + final LN
// ---------------------------------------------------------------------------
__global__ __launch_bounds__(256) void k_ffn2ln(
    const float* __restrict__ Hd, const float* __restrict__ W2,
    const float* __restrict__ b2, const float* __restrict__ res,
    const float* __restrict__ g, const float* __restrict__ be,
    float* __restrict__ out) {
  __shared__ float Ws[256][64];  // 64 KB
  int tid = threadIdx.x;
  int lane = tid & 63, w = tid >> 6;
  for (int i = tid; i < 256 * 64; i += 256) Ws[i >> 6][i & 63] = W2[i];
  __syncthreads();
  int row = blockIdx.x * 4 + w;
  const float* hr = Hd + (size_t)row * 256;
  float acc = b2[lane] + res[(size_t)row * 64 + lane];
#pragma unroll
  for (int c = 0; c < 4; ++c) {
    float hv = hr[c * 64 + lane];
#pragma unroll
    for (int i = 0; i < 64; ++i) acc += __shfl(hv, i, 64) * Ws[c * 64 + i][lane];
  }
  float s = acc;
#pragma unroll
  for (int off = 32; off; off >>= 1) s += __shfl_xor(s, off, 64);
  float mean = s * (1.f / 64.f);
  float d = acc - mean;
  float v = d * d;
#pragma unroll
  for (int off = 32; off; off >>= 1) v += __shfl_xor(v, off, 64);
  float rstd = rsqrtf(v * (1.f / 64.f) + 1e-5f);
  out[(size_t)row * 64 + lane] = d * rstd * g[lane] + be[lane];
}

// ---------------------------------------------------------------------------
extern "C" void kernel_launch(void* const* d_in, const int* in_sizes, int n_in,
                              void* d_out, int out_size, void* d_ws,
                              size_t ws_size, hipStream_t stream) {
  const float* x = (const float*)d_in[0];
  const float* adj = (const float*)d_in[1];
  const float* W_gp = (const float*)d_in[2];
  const float* b_gp = (const float*)d_in[3];
  const float* Wq_s = (const float*)d_in[4];
  const float* Wk_s = (const float*)d_in[5];
  const float* Wv_s = (const float*)d_in[6];
  const float* Wo_s = (const float*)d_in[7];
  const float* bq_s = (const float*)d_in[8];
  const float* bk_s = (const float*)d_in[9];
  const float* bv_s = (const float*)d_in[10];
  const float* bo_s = (const float*)d_in[11];
  const float* g_s = (const float*)d_in[12];
  const float* be_s = (const float*)d_in[13];
  const float* Wq_t = (const float*)d_in[14];
  const float* Wk_t = (const float*)d_in[15];
  const float* Wv_t = (const float*)d_in[16];
  const float* Wo_t = (const float*)d_in[17];
  const float* bq_t = (const float*)d_in[18];
  const float* bk_t = (const float*)d_in[19];
  const float* bv_t = (const float*)d_in[20];
  const float* bo_t = (const float*)d_in[21];
  const float* g_t = (const float*)d_in[22];
  const float* be_t = (const float*)d_in[23];
  const float* W1 = (const float*)d_in[24];
  const float* b1 = (const float*)d_in[25];
  const float* W2 = (const float*)d_in[26];
  const float* b2 = (const float*)d_in[27];
  const float* g1 = (const float*)d_in[28];
  const float* be1 = (const float*)d_in[29];
  const float* g2 = (const float*)d_in[30];
  const float* be2 = (const float*)d_in[31];
  float* out = (float*)d_out;

  float* ws = (float*)d_ws;
  const size_t U = (size_t)NR * 64;  // 1,228,800 floats
  float* A = ws + 0 * U;
  float* Bb = ws + 1 * U;
  float* C = ws + 2 * U;
  float* D = ws + 3 * U;
  float* P = ws + 4 * U;
  // region 5U..9U: PB (bf16, first 0.5U) during qkv; PART during sattn; HID in FFN
  unsigned short* PB = (unsigned short*)(ws + 5 * U);  // 0.5U as bf16
  float* Pm = ws + 5 * U;            // KSPLIT*NQ           (sattn phase)
  float* Pl = Pm + (size_t)KSPLIT * NQ;
  float* Po = Pl + (size_t)KSPLIT * NQ;  // KSPLIT*NQ*8 ; total exactly 5U
  float* HID = ws + 5 * U;                              // NR x 256 = 4U (FFN)
  unsigned short* HB0 = (unsigned short*)(ws + 9 * U);  // bf16, 0.5U
  unsigned short* HB1 = (unsigned short*)(ws + 9 * U + U / 2);
  unsigned short* ADJB = (unsigned short*)(ws + 10 * U);  // bf16, 0.52U
  unsigned short* WB = (unsigned short*)(ws + 10 * U + 650240);  // 6*4096 bf16

  dim3 blk(256);
  // 0) conversions
  k_w2bf<<<dim3(16, 6), blk, 0, stream>>>(Wq_s, Wk_s, Wv_s, Wq_t, Wk_t, Wv_t,
                                          WB);
  k_adjbf<<<(NB * NN * NN / 4 + 255) / 256, blk, 0, stream>>>(adj, ADJB);
  // 1) scale + graph linear -> HB0 (bf16)
  k_scale_gp<<<NR / 16, blk, 0, stream>>>(x, W_gp, b_gp, HB0);
  // 2) 3 MFMA propagation steps; residual fused into last -> P (f32) + PB
  k_prop_mfma<false><<<NBS * 25, blk, 0, stream>>>(ADJB, HB0, x, HB1, P, PB);
  k_prop_mfma<false><<<NBS * 25, blk, 0, stream>>>(ADJB, HB1, x, HB0, P, PB);
  k_prop_mfma<true><<<NBS * 25, blk, 0, stream>>>(ADJB, HB0, x, HB1, P, PB);
  // 3) spatial QKV (MFMA) -> A,Bb,C ; attn partials+combine -> D ; proj+LN -> A
  k_qkv_mfma<<<NR / 32, blk, 0, stream>>>(PB, WB, WB + 4096, WB + 8192, bq_s,
                                          bk_s, bv_s, A, Bb, C);
  k_sattn_part<<<dim3(NBS, HEADS, 4 * KSPLIT), dim3(64), 0, stream>>>(
      A, Bb, C, Pm, Pl, Po);
  k_sattn_comb<<<(NQ + 255) / 256, blk, 0, stream>>>(Pm, Pl, Po, D);
  k_projln<<<NR / 4, blk, 0, stream>>>(D, Wo_s, bo_s, P, g_s, be_s, A, PB);
  // 4) temporal QKV (MFMA) -> Bb,C,D ; attn -> P ; proj+LN -> Bb (res = A)
  k_qkv_mfma<<<NR / 32, blk, 0, stream>>>(PB, WB + 12288, WB + 16384,
                                          WB + 20480, bq_t, bk_t, bv_t, Bb, C,
                                          D);
  k_tattn<<<NB * NN, blk, 0, stream>>>(Bb, C, D, P);
  k_projln<<<NR / 4, blk, 0, stream>>>(P, Wo_t, bo_t, A, g_t, be_t, Bb,
                                       (unsigned short*)nullptr);
  // 5) FFN: LN1 -> C ; hid -> HID ; W2 + residual + final LN -> out
  k_ln<<<NR / 4, blk, 0, stream>>>(Bb, g1, be1, C);
  k_ffn1<<<NR / 16, blk, 0, stream>>>(C, W1, b1, HID);
  k_ffn2ln<<<NR / 4, blk, 0, stream>>>(HID, W2, b2, Bb, g2, be2, out);
}

// Round 5
// 248.354 us; speedup vs baseline: 2.6839x; 1.7773x over previous
//
#include <hip/hip_runtime.h>
#include <hip/hip_bf16.h>

#define NB 2
#define NS 12
#define NN 800
#define HEADS 8
#define DH 8
#define NBS (NB*NS)        // 24
#define NR (NB*NS*NN)      // 19200 rows

typedef __attribute__((ext_vector_type(4))) float f32x4;
typedef __attribute__((ext_vector_type(4))) short s16x4;
typedef __attribute__((ext_vector_type(8))) short s16x8;

static __device__ __forceinline__ unsigned short f2bf(float f) {
  union { float f; unsigned u; } v; v.f = f;
  unsigned r = (v.u + 0x7FFFu + ((v.u >> 16) & 1u)) >> 16;
  return (unsigned short)r;
}
static __device__ __forceinline__ float bf2f(unsigned short u) {
  union { unsigned u; float f; } v;
  v.u = ((unsigned)u) << 16;
  return v.f;
}
static __device__ __forceinline__ float fexp2(float x) {
  return __builtin_amdgcn_exp2f(x);  // v_exp_f32
}

// ---------------------------------------------------------------------------
// 0a) adj f32 -> bf16
// ---------------------------------------------------------------------------
__global__ __launch_bounds__(256) void k_adjbf(const float* __restrict__ adj,
                                               unsigned short* __restrict__ o) {
  int i = blockIdx.x * 256 + threadIdx.x;
  if (i >= NB * NN * NN / 4) return;
  float4 a = *(const float4*)(adj + (size_t)i * 4);
  ushort4 r;
  r.x = f2bf(a.x); r.y = f2bf(a.y); r.z = f2bf(a.z); r.w = f2bf(a.w);
  *(ushort4*)(o + (size_t)i * 4) = r;
}

// ---------------------------------------------------------------------------
// 0b) 7 64x64 weight matrices f32 -> bf16
// ---------------------------------------------------------------------------
__global__ __launch_bounds__(256) void k_w2bf(
    const float* __restrict__ w0, const float* __restrict__ w1,
    const float* __restrict__ w2, const float* __restrict__ w3,
    const float* __restrict__ w4, const float* __restrict__ w5,
    const float* __restrict__ w6, unsigned short* __restrict__ out) {
  const float* ws[7] = {w0, w1, w2, w3, w4, w5, w6};
  int y = blockIdx.y;
  int i = blockIdx.x * 256 + threadIdx.x;
  if (i < 4096) out[y * 4096 + i] = f2bf(ws[y][i]);
}

// ---------------------------------------------------------------------------
// 0c) generic f32 -> bf16 copy
// ---------------------------------------------------------------------------
__global__ __launch_bounds__(256) void k_f2bf(const float* __restrict__ src,
                                              unsigned short* __restrict__ dst,
                                              int n) {
  int i = blockIdx.x * 256 + threadIdx.x;
  if (i < n) dst[i] = f2bf(src[i]);
}

// ---------------------------------------------------------------------------
// 1a) xs = x*(1+0.3*x[..,62]*exp(-x[..,63]/60))  -> bf16 (wave per row)
// ---------------------------------------------------------------------------
__global__ __launch_bounds__(256) void k_xscale(const float* __restrict__ x,
                                                unsigned short* __restrict__ o) {
  int tid = threadIdx.x;
  int lane = tid & 63, w = tid >> 6;
  int row = blockIdx.x * 4 + w;
  float v = x[(size_t)row * 64 + lane];
  float a62 = __shfl(v, 62, 64);
  float a63 = __shfl(v, 63, 64);
  float sf = 1.0f + 0.3f * a62 * __expf(-a63 * (1.0f / 60.0f));
  o[(size_t)row * 64 + lane] = f2bf(v * sf);
}

// ---------------------------------------------------------------------------
// 1b) generic MFMA linear 64->64: out_bf16 = Xb @ Wb + b
// ---------------------------------------------------------------------------
__global__ __launch_bounds__(256) void k_lin64_mfma(
    const unsigned short* __restrict__ Xb, const unsigned short* __restrict__ Wb,
    const float* __restrict__ bias, unsigned short* __restrict__ out) {
  __shared__ unsigned short As[32][36];
  __shared__ unsigned short Bs[64][36];
  const int tid = threadIdx.x;
  const int r0 = blockIdx.x * 32;
  const int w = tid >> 6, l = tid & 63;
  const int rb = (w & 1) * 16, cb = (w >> 1) * 32;
  f32x4 acc0 = {0.f, 0.f, 0.f, 0.f}, acc1 = {0.f, 0.f, 0.f, 0.f};
  const int ar = tid >> 3, ak = (tid & 7) * 4;
  const int bc = tid & 63, bm0 = (tid >> 6) * 4;
  const int k4 = (l >> 4) * 4;
  const int arow = rb + (l & 15);
  const int bcol0 = cb + (l & 15);
  for (int k0 = 0; k0 < 64; k0 += 32) {
    __syncthreads();
    *(s16x4*)&As[ar][ak] = *(const s16x4*)(Xb + (size_t)(r0 + ar) * 64 + k0 + ak);
#pragma unroll
    for (int j = 0; j < 4; ++j) {
      int mp = bm0 + j;
      unsigned lo = Wb[(size_t)(k0 + 2 * mp) * 64 + bc];
      unsigned hi = Wb[(size_t)(k0 + 2 * mp + 1) * 64 + bc];
      *(unsigned*)&Bs[bc][2 * mp] = lo | (hi << 16);
    }
    __syncthreads();
    s16x4 alo = *(const s16x4*)&As[arow][k4];
    s16x4 ahi = *(const s16x4*)&As[arow][k4 + 16];
    s16x8 a = {alo.x, alo.y, alo.z, alo.w, ahi.x, ahi.y, ahi.z, ahi.w};
    s16x4 b0l = *(const s16x4*)&Bs[bcol0][k4];
    s16x4 b0h = *(const s16x4*)&Bs[bcol0][k4 + 16];
    s16x8 bf0 = {b0l.x, b0l.y, b0l.z, b0l.w, b0h.x, b0h.y, b0h.z, b0h.w};
    s16x4 b1l = *(const s16x4*)&Bs[bcol0 + 16][k4];
    s16x4 b1h = *(const s16x4*)&Bs[bcol0 + 16][k4 + 16];
    s16x8 bf1 = {b1l.x, b1l.y, b1l.z, b1l.w, b1h.x, b1h.y, b1h.z, b1h.w};
    acc0 = __builtin_amdgcn_mfma_f32_16x16x32_bf16(a, bf0, acc0, 0, 0, 0);
    acc1 = __builtin_amdgcn_mfma_f32_16x16x32_bf16(a, bf1, acc1, 0, 0, 0);
  }
  const int c0 = cb + (l & 15);
  float b0 = bias[c0], b1 = bias[c0 + 16];
#pragma unroll
  for (int r = 0; r < 4; ++r) {
    int row = r0 + rb + (l >> 4) * 4 + r;
    out[(size_t)row * 64 + c0] = f2bf(acc0[r] + b0);
    out[(size_t)row * 64 + c0 + 16] = f2bf(acc1[r] + b1);
  }
}

// ---------------------------------------------------------------------------
// 2) MFMA graph propagation: h' = relu(adj @ h)
//    LAST: pout = relu(adj@h) + x (f32)  AND  pbout = bf16(pout)
// ---------------------------------------------------------------------------
template <bool LAST>
__global__ __launch_bounds__(256) void k_prop_mfma(
    const unsigned short* __restrict__ adjB,
    const unsigned short* __restrict__ hin,
    const float* __restrict__ x,
    unsigned short* __restrict__ hout,
    float* __restrict__ pout,
    unsigned short* __restrict__ pbout) {
  __shared__ unsigned short As[32][36];
  __shared__ unsigned short Bs[64][36];
  const int tid = threadIdx.x;
  const int bid = blockIdx.x;
  const int bs = bid / 25, mt = bid % 25;
  const int b = bs / NS;
  const int n0 = mt * 32;
  const unsigned short* abase = adjB + (size_t)b * NN * NN + (size_t)n0 * NN;
  const unsigned short* hbase = hin + (size_t)bs * NN * 64;
  const int w = tid >> 6, l = tid & 63;
  const int rb = (w & 1) * 16;
  const int cb = (w >> 1) * 32;
  f32x4 acc0 = {0.f, 0.f, 0.f, 0.f}, acc1 = {0.f, 0.f, 0.f, 0.f};
  const int ar = tid >> 3, ak = (tid & 7) * 4;
  const int bc = tid & 63, bm0 = (tid >> 6) * 4;
  const int k4 = (l >> 4) * 4;
  const int arow = rb + (l & 15);
  const int bcol0 = cb + (l & 15);
  for (int m0 = 0; m0 < NN; m0 += 32) {
    __syncthreads();
    *(s16x4*)&As[ar][ak] =
        *(const s16x4*)(abase + (size_t)ar * NN + m0 + ak);
#pragma unroll
    for (int j = 0; j < 4; ++j) {
      int mp = bm0 + j;
      unsigned lo = hbase[(size_t)(m0 + 2 * mp) * 64 + bc];
      unsigned hi = hbase[(size_t)(m0 + 2 * mp + 1) * 64 + bc];
      *(unsigned*)&Bs[bc][2 * mp] = lo | (hi << 16);
    }
    __syncthreads();
    s16x4 alo = *(const s16x4*)&As[arow][k4];
    s16x4 ahi = *(const s16x4*)&As[arow][k4 + 16];
    s16x8 a = {alo.x, alo.y, alo.z, alo.w, ahi.x, ahi.y, ahi.z, ahi.w};
    s16x4 b0l = *(const s16x4*)&Bs[bcol0][k4];
    s16x4 b0h = *(const s16x4*)&Bs[bcol0][k4 + 16];
    s16x8 bf0 = {b0l.x, b0l.y, b0l.z, b0l.w, b0h.x, b0h.y, b0h.z, b0h.w};
    s16x4 b1l = *(const s16x4*)&Bs[bcol0 + 16][k4];
    s16x4 b1h = *(const s16x4*)&Bs[bcol0 + 16][k4 + 16];
    s16x8 bf1 = {b1l.x, b1l.y, b1l.z, b1l.w, b1h.x, b1h.y, b1h.z, b1h.w};
    acc0 = __builtin_amdgcn_mfma_f32_16x16x32_bf16(a, bf0, acc0, 0, 0, 0);
    acc1 = __builtin_amdgcn_mfma_f32_16x16x32_bf16(a, bf1, acc1, 0, 0, 0);
  }
#pragma unroll
  for (int r = 0; r < 4; ++r) {
    int n = n0 + rb + (l >> 4) * 4 + r;
    int c0 = cb + (l & 15);
    float v0 = fmaxf(acc0[r], 0.f);
    float v1 = fmaxf(acc1[r], 0.f);
    size_t i0 = ((size_t)bs * NN + n) * 64 + c0;
    size_t i1 = i0 + 16;
    if (LAST) {
      float p0 = v0 + x[i0], p1 = v1 + x[i1];
      pout[i0] = p0;
      pout[i1] = p1;
      pbout[i0] = f2bf(p0);
      pbout[i1] = f2bf(p1);
    } else {
      hout[i0] = f2bf(v0);
      hout[i1] = f2bf(v1);
    }
  }
}

// ---------------------------------------------------------------------------
// 3) MFMA fused QKV; BFOUT: bf16 outputs (spatial), else f32 (temporal)
// ---------------------------------------------------------------------------
template <bool BFOUT>
__global__ __launch_bounds__(256) void k_qkv_mfma(
    const unsigned short* __restrict__ Xb,
    const unsigned short* __restrict__ Wq,
    const unsigned short* __restrict__ Wk,
    const unsigned short* __restrict__ Wv,
    const float* __restrict__ bq, const float* __restrict__ bk,
    const float* __restrict__ bv,
    void* __restrict__ Qo, void* __restrict__ Ko, void* __restrict__ Vo) {
  __shared__ unsigned short As[32][36];
  __shared__ unsigned short Bs[3][64][36];
  const int tid = threadIdx.x;
  const int r0 = blockIdx.x * 32;
  const int w = tid >> 6, l = tid & 63;
  const int rb = (w & 1) * 16;
  const int cb = (w >> 1) * 32;
  f32x4 acc[3][2];
#pragma unroll
  for (int i = 0; i < 3; ++i)
#pragma unroll
    for (int j = 0; j < 2; ++j) acc[i][j] = (f32x4){0.f, 0.f, 0.f, 0.f};
  const unsigned short* Wm[3] = {Wq, Wk, Wv};
  const int ar = tid >> 3, ak = (tid & 7) * 4;
  const int bc = tid & 63, bm0 = (tid >> 6) * 4;
  const int k4 = (l >> 4) * 4;
  const int arow = rb + (l & 15);
  const int bcol0 = cb + (l & 15);
  for (int k0 = 0; k0 < 64; k0 += 32) {
    __syncthreads();
    *(s16x4*)&As[ar][ak] =
        *(const s16x4*)(Xb + (size_t)(r0 + ar) * 64 + k0 + ak);
#pragma unroll
    for (int wm = 0; wm < 3; ++wm) {
#pragma unroll
      for (int j = 0; j < 4; ++j) {
        int mp = bm0 + j;
        unsigned lo = Wm[wm][(size_t)(k0 + 2 * mp) * 64 + bc];
        unsigned hi = Wm[wm][(size_t)(k0 + 2 * mp + 1) * 64 + bc];
        *(unsigned*)&Bs[wm][bc][2 * mp] = lo | (hi << 16);
      }
    }
    __syncthreads();
    s16x4 alo = *(const s16x4*)&As[arow][k4];
    s16x4 ahi = *(const s16x4*)&As[arow][k4 + 16];
    s16x8 a = {alo.x, alo.y, alo.z, alo.w, ahi.x, ahi.y, ahi.z, ahi.w};
#pragma unroll
    for (int wm = 0; wm < 3; ++wm) {
      s16x4 b0l = *(const s16x4*)&Bs[wm][bcol0][k4];
      s16x4 b0h = *(const s16x4*)&Bs[wm][bcol0][k4 + 16];
      s16x8 bf0 = {b0l.x, b0l.y, b0l.z, b0l.w, b0h.x, b0h.y, b0h.z, b0h.w};
      s16x4 b1l = *(const s16x4*)&Bs[wm][bcol0 + 16][k4];
      s16x4 b1h = *(const s16x4*)&Bs[wm][bcol0 + 16][k4 + 16];
      s16x8 bf1 = {b1l.x, b1l.y, b1l.z, b1l.w, b1h.x, b1h.y, b1h.z, b1h.w};
      acc[wm][0] = __builtin_amdgcn_mfma_f32_16x16x32_bf16(a, bf0, acc[wm][0], 0, 0, 0);
      acc[wm][1] = __builtin_amdgcn_mfma_f32_16x16x32_bf16(a, bf1, acc[wm][1], 0, 0, 0);
    }
  }
  const float* bm[3] = {bq, bk, bv};
  const int c0 = cb + (l & 15);
#pragma unroll
  for (int wm = 0; wm < 3; ++wm) {
    float b0 = bm[wm][c0], b1 = bm[wm][c0 + 16];
#pragma unroll
    for (int r = 0; r < 4; ++r) {
      int row = r0 + rb + (l >> 4) * 4 + r;
      float v0 = acc[wm][0][r] + b0;
      float v1 = acc[wm][1][r] + b1;
      if (BFOUT) {
        unsigned short* Om = (unsigned short*)(wm == 0 ? Qo : (wm == 1 ? Ko : Vo));
        Om[(size_t)row * 64 + c0] = f2bf(v0);
        Om[(size_t)row * 64 + c0 + 16] = f2bf(v1);
      } else {
        float* Om = (float*)(wm == 0 ? Qo : (wm == 1 ? Ko : Vo));
        Om[(size_t)row * 64 + c0] = v0;
        Om[(size_t)row * 64 + c0 + 16] = v1;
      }
    }
  }
}

// ---------------------------------------------------------------------------
// 4) spatial attention, MFMA QK^T + VALU flash PV.
//    Block = (bs, h, 64-query chunk), 4 waves x 16 queries.
// ---------------------------------------------------------------------------
#define SC_LOG2 (0.35355339059327373f * 1.44269504088896f)

__global__ __launch_bounds__(256) void k_sattn_mfma(
    const unsigned short* __restrict__ Qb,
    const unsigned short* __restrict__ Kb,
    const unsigned short* __restrict__ Vb,
    float* __restrict__ O) {
  __shared__ unsigned short Ks[800][8];
  __shared__ unsigned short Vs[800][8];
  const int bs = blockIdx.x, h = blockIdx.y;
  const int tid = threadIdx.x;
  const int w = tid >> 6, l = tid & 63;
  const size_t base = (size_t)bs * NN * 64 + h * DH;
  for (int r = tid; r < NN; r += 256) {
    *(s16x4*)&Ks[r][0] = *(const s16x4*)(Kb + base + (size_t)r * 64);
    *(s16x4*)&Ks[r][4] = *(const s16x4*)(Kb + base + (size_t)r * 64 + 4);
    *(s16x4*)&Vs[r][0] = *(const s16x4*)(Vb + base + (size_t)r * 64);
    *(s16x4*)&Vs[r][4] = *(const s16x4*)(Vb + base + (size_t)r * 64 + 4);
  }
  __syncthreads();
  const int q0 = blockIdx.z * 64 + w * 16;
  if (q0 >= NN) return;
  const int r15 = l & 15;
  const int k4 = (l >> 4) * 4;
  s16x8 qf = {0, 0, 0, 0, 0, 0, 0, 0};
  if (k4 < 8) {
    s16x4 qv = *(const s16x4*)(Qb + base + (size_t)(q0 + r15) * 64 + k4);
    qf[0] = qv.x; qf[1] = qv.y; qf[2] = qv.z; qf[3] = qv.w;
  }
  float m[4], ls[4], o[4][8];
#pragma unroll
  for (int r = 0; r < 4; ++r) {
    m[r] = -1e30f;
    ls[r] = 0.f;
#pragma unroll
    for (int d = 0; d < 8; ++d) o[r][d] = 0.f;
  }
  for (int kc = 0; kc < 5; ++kc) {
    const int kb = kc * 160;
    f32x4 s[10];
#pragma unroll
    for (int t = 0; t < 10; ++t) {
      s16x8 kf = {0, 0, 0, 0, 0, 0, 0, 0};
      if (k4 < 8) {
        s16x4 kv = *(const s16x4*)&Ks[kb + t * 16 + r15][k4];
        kf[0] = kv.x; kf[1] = kv.y; kf[2] = kv.z; kf[3] = kv.w;
      }
      s[t] = __builtin_amdgcn_mfma_f32_16x16x32_bf16(
          qf, kf, (f32x4){0.f, 0.f, 0.f, 0.f}, 0, 0, 0);
    }
    // row max (log2-scaled domain), reduce over the 16 key-lanes
#pragma unroll
    for (int r = 0; r < 4; ++r) {
      float v = s[0][r];
#pragma unroll
      for (int t = 1; t < 10; ++t) v = fmaxf(v, s[t][r]);
#pragma unroll
      for (int off = 1; off < 16; off <<= 1)
        v = fmaxf(v, __shfl_xor(v, off, 64));
      float tm = v * SC_LOG2;
      float mn = fmaxf(m[r], tm);
      float corr = fexp2(m[r] - mn);
      m[r] = mn;
      ls[r] *= corr;
#pragma unroll
      for (int d = 0; d < 8; ++d) o[r][d] *= corr;
    }
    // p = exp2(s*c - m); PV accumulate in f32 (lane-partial)
#pragma unroll
    for (int t = 0; t < 10; ++t) {
      int key = kb + t * 16 + r15;
      s16x4 v0 = *(const s16x4*)&Vs[key][0];
      s16x4 v1 = *(const s16x4*)&Vs[key][4];
      float vv[8];
      vv[0] = bf2f(v0.x); vv[1] = bf2f(v0.y); vv[2] = bf2f(v0.z); vv[3] = bf2f(v0.w);
      vv[4] = bf2f(v1.x); vv[5] = bf2f(v1.y); vv[6] = bf2f(v1.z); vv[7] = bf2f(v1.w);
#pragma unroll
      for (int r = 0; r < 4; ++r) {
        float p = fexp2(fmaf(s[t][r], SC_LOG2, -m[r]));
        ls[r] += p;
#pragma unroll
        for (int d = 0; d < 8; ++d) o[r][d] = fmaf(p, vv[d], o[r][d]);
      }
    }
  }
  // final reduce over the 16 key-lanes
#pragma unroll
  for (int r = 0; r < 4; ++r) {
#pragma unroll
    for (int off = 1; off < 16; off <<= 1) ls[r] += __shfl_xor(ls[r], off, 64);
#pragma unroll
    for (int d = 0; d < 8; ++d) {
#pragma unroll
      for (int off = 1; off < 16; off <<= 1)
        o[r][d] += __shfl_xor(o[r][d], off, 64);
    }
  }
  float inv[4];
#pragma unroll
  for (int r = 0; r < 4; ++r) inv[r] = 1.f / ls[r];
#pragma unroll
  for (int d = 0; d < 8; ++d) {
    if (r15 == d) {
#pragma unroll
      for (int r = 0; r < 4; ++r) {
        int q = q0 + (l >> 4) * 4 + r;
        O[base + (size_t)q * 64 + d] = o[r][d] * inv[r];
      }
    }
  }
}

// ---------------------------------------------------------------------------
// 5) y = LN(X@W + b + res; g, be)  (wave per row), optional bf16 copy out
// ---------------------------------------------------------------------------
__global__ __launch_bounds__(256) void k_projln(
    const float* __restrict__ X, const float* __restrict__ W,
    const float* __restrict__ bias, const float* __restrict__ res,
    const float* __restrict__ g, const float* __restrict__ be,
    float* __restrict__ out, unsigned short* __restrict__ bfout) {
  __shared__ float Ws[64][64];
  int tid = threadIdx.x;
  int lane = tid & 63, w = tid >> 6;
  for (int i = tid; i < 4096; i += 256) Ws[i >> 6][i & 63] = W[i];
  __syncthreads();
  int row = blockIdx.x * 4 + w;
  float xv = X[(size_t)row * 64 + lane];
  float acc = bias[lane];
#pragma unroll
  for (int i = 0; i < 64; ++i) acc += __shfl(xv, i, 64) * Ws[i][lane];
  acc += res[(size_t)row * 64 + lane];
  float s = acc;
#pragma unroll
  for (int off = 32; off; off >>= 1) s += __shfl_xor(s, off, 64);
  float mean = s * (1.f / 64.f);
  float d = acc - mean;
  float v = d * d;
#pragma unroll
  for (int off = 32; off; off >>= 1) v += __shfl_xor(v, off, 64);
  float rstd = rsqrtf(v * (1.f / 64.f) + 1e-5f);
  float r = d * rstd * g[lane] + be[lane];
  out[(size_t)row * 64 + lane] = r;
  if (bfout) bfout[(size_t)row * 64 + lane] = f2bf(r);
}

// ---------------------------------------------------------------------------
// 6) temporal attention: one block per (b,n), L = 12
// ---------------------------------------------------------------------------
__global__ __launch_bounds__(256) void k_tattn(const float* __restrict__ Q,
                                               const float* __restrict__ K,
                                               const float* __restrict__ V,
                                               float* __restrict__ O) {
  int b = blockIdx.x / NN, n = blockIdx.x % NN;
  __shared__ float Qs[12][64], Ks[12][64], Vs[12][64];
  int tid = threadIdx.x;
  for (int i = tid; i < 12 * 64; i += 256) {
    int s = i >> 6, c = i & 63;
    size_t idx = (((size_t)b * NS + s) * NN + n) * 64 + c;
    Qs[s][c] = Q[idx];
    Ks[s][c] = K[idx];
    Vs[s][c] = V[idx];
  }
  __syncthreads();
  for (int wi = tid; wi < 12 * 64; wi += 256) {
    int l = wi >> 6, c = wi & 63;
    int h8 = c & 56;
    float sc[12];
    float mx = -1e30f;
#pragma unroll
    for (int m = 0; m < 12; ++m) {
      float s = 0.f;
#pragma unroll
      for (int d = 0; d < 8; ++d) s += Qs[l][h8 + d] * Ks[m][h8 + d];
      s *= 0.35355339059327373f;
      sc[m] = s;
      mx = fmaxf(mx, s);
    }
    float sum = 0.f;
#pragma unroll
    for (int m = 0; m < 12; ++m) {
      sc[m] = __expf(sc[m] - mx);
      sum += sc[m];
    }
    float inv = 1.f / sum;
    float o = 0.f;
#pragma unroll
    for (int m = 0; m < 12; ++m) o += sc[m] * Vs[m][c];
    size_t idx = (((size_t)b * NS + l) * NN + n) * 64 + c;
    O[idx] = o * inv;
  }
}

// ---------------------------------------------------------------------------
// 7) plain LN (wave per row) -> bf16
// ---------------------------------------------------------------------------
__global__ __launch_bounds__(256) void k_ln(const float* __restrict__ X,
                                            const float* __restrict__ g,
                                            const float* __restrict__ be,
                                            unsigned short* __restrict__ out) {
  int tid = threadIdx.x;
  int lane = tid & 63, w = tid >> 6;
  int row = blockIdx.x * 4 + w;
  float acc = X[(size_t)row * 64 + lane];
  float s = acc;
#pragma unroll
  for (int off = 32; off; off >>= 1) s += __shfl_xor(s, off, 64);
  float mean = s * (1.f / 64.f);
  float d = acc - mean;
  float v = d * d;
#pragma unroll
  for (int off = 32; off; off >>= 1) v += __shfl_xor(v, off, 64);
  float rstd = rsqrtf(v * (1.f / 64.f) + 1e-5f);
  out[(size_t)row * 64 + lane] = f2bf(d * rstd * g[lane] + be[lane]);
}

// ---------------------------------------------------------------------------
// 8) FFN1 MFMA: HIDB = bf16(relu(LNB @ W1b + b1)); W1 is 64x256
//    grid: (NR/32, 4) — blockIdx.y selects 64-col chunk
// ---------------------------------------------------------------------------
__global__ __launch_bounds__(256) void k_ffn1_mfma(
    const unsigned short* __restrict__ Xb,
    const unsigned short* __restrict__ W1b,  // [64][256]
    const float* __restrict__ b1, unsigned short* __restrict__ Hid) {
  __shared__ unsigned short As[32][36];
  __shared__ unsigned short Bs[64][36];
  const int tid = threadIdx.x;
  const int r0 = blockIdx.x * 32;
  const int n0 = blockIdx.y * 64;
  const int w = tid >> 6, l = tid & 63;
  const int rb = (w & 1) * 16, cb = (w >> 1) * 32;
  f32x4 acc0 = {0.f, 0.f, 0.f, 0.f}, acc1 = {0.f, 0.f, 0.f, 0.f};
  const int ar = tid >> 3, ak = (tid & 7) * 4;
  const int bc = tid & 63, bm0 = (tid >> 6) * 4;
  const int k4 = (l >> 4) * 4;
  const int arow = rb + (l & 15);
  const int bcol0 = cb + (l & 15);
  for (int k0 = 0; k0 < 64; k0 += 32) {
    __syncthreads();
    *(s16x4*)&As[ar][ak] = *(const s16x4*)(Xb + (size_t)(r0 + ar) * 64 + k0 + ak);
#pragma unroll
    for (int j = 0; j < 4; ++j) {
      int mp = bm0 + j;
      unsigned lo = W1b[(size_t)(k0 + 2 * mp) * 256 + n0 + bc];
      unsigned hi = W1b[(size_t)(k0 + 2 * mp + 1) * 256 + n0 + bc];
      *(unsigned*)&Bs[bc][2 * mp] = lo | (hi << 16);
    }
    __syncthreads();
    s16x4 alo = *(const s16x4*)&As[arow][k4];
    s16x4 ahi = *(const s16x4*)&As[arow][k4 + 16];
    s16x8 a = {alo.x, alo.y, alo.z, alo.w, ahi.x, ahi.y, ahi.z, ahi.w};
    s16x4 b0l = *(const s16x4*)&Bs[bcol0][k4];
    s16x4 b0h = *(const s16x4*)&Bs[bcol0][k4 + 16];
    s16x8 bf0 = {b0l.x, b0l.y, b0l.z, b0l.w, b0h.x, b0h.y, b0h.z, b0h.w};
    s16x4 b1l = *(const s16x4*)&Bs[bcol0 + 16][k4];
    s16x4 b1h = *(const s16x4*)&Bs[bcol0 + 16][k4 + 16];
    s16x8 bf1 = {b1l.x, b1l.y, b1l.z, b1l.w, b1h.x, b1h.y, b1h.z, b1h.w};
    acc0 = __builtin_amdgcn_mfma_f32_16x16x32_bf16(a, bf0, acc0, 0, 0, 0);
    acc1 = __builtin_amdgcn_mfma_f32_16x16x32_bf16(a, bf1, acc1, 0, 0, 0);
  }
  const int c0 = cb + (l & 15);
  float b0 = b1[n0 + c0], bb1 = b1[n0 + c0 + 16];
#pragma unroll
  for (int r = 0; r < 4; ++r) {
    int row = r0 + rb + (l >> 4) * 4 + r;
    Hid[(size_t)row * 256 + n0 + c0] = f2bf(fmaxf(acc0[r] + b0, 0.f));
    Hid[(size_t)row * 256 + n0 + c0 + 16] = f2bf(fmaxf(acc1[r] + bb1, 0.f));
  }
}

// ---------------------------------------------------------------------------
// 9) FFN2 MFMA + residual + final LN: out = LN(Hid @ W2 + b2 + res)
// ---------------------------------------------------------------------------
__global__ __launch_bounds__(256) void k_ffn2ln_mfma(
    const unsigned short* __restrict__ Hd,   // [NR][256] bf16
    const unsigned short* __restrict__ W2b,  // [256][64] bf16
    const float* __restrict__ b2, const float* __restrict__ res,
    const float* __restrict__ g, const float* __restrict__ be,
    float* __restrict__ out) {
  __shared__ unsigned short As[32][36];
  __shared__ unsigned short Bs[64][36];
  __shared__ float CT[32][68];
  const int tid = threadIdx.x;
  const int r0 = blockIdx.x * 32;
  const int w = tid >> 6, l = tid & 63;
  const int rb = (w & 1) * 16, cb = (w >> 1) * 32;
  f32x4 acc0 = {0.f, 0.f, 0.f, 0.f}, acc1 = {0.f, 0.f, 0.f, 0.f};
  const int ar = tid >> 3, ak = (tid & 7) * 4;
  const int bc = tid & 63, bm0 = (tid >> 6) * 4;
  const int k4 = (l >> 4) * 4;
  const int arow = rb + (l & 15);
  const int bcol0 = cb + (l & 15);
  for (int k0 = 0; k0 < 256; k0 += 32) {
    __syncthreads();
    *(s16x4*)&As[ar][ak] = *(const s16x4*)(Hd + (size_t)(r0 + ar) * 256 + k0 + ak);
#pragma unroll
    for (int j = 0; j < 4; ++j) {
      int mp = bm0 + j;
      unsigned lo = W2b[(size_t)(k0 + 2 * mp) * 64 + bc];
      unsigned hi = W2b[(size_t)(k0 + 2 * mp + 1) * 64 + bc];
      *(unsigned*)&Bs[bc][2 * mp] = lo | (hi << 16);
    }
    __syncthreads();
    s16x4 alo = *(const s16x4*)&As[arow][k4];
    s16x4 ahi = *(const s16x4*)&As[arow][k4 + 16];
    s16x8 a = {alo.x, alo.y, alo.z, alo.w, ahi.x, ahi.y, ahi.z, ahi.w};
    s16x4 b0l = *(const s16x4*)&Bs[bcol0][k4];
    s16x4 b0h = *(const s16x4*)&Bs[bcol0][k4 + 16];
    s16x8 bf0 = {b0l.x, b0l.y, b0l.z, b0l.w, b0h.x, b0h.y, b0h.z, b0h.w};
    s16x4 b1l = *(const s16x4*)&Bs[bcol0 + 16][k4];
    s16x4 b1h = *(const s16x4*)&Bs[bcol0 + 16][k4 + 16];
    s16x8 bf1 = {b1l.x, b1l.y, b1l.z, b1l.w, b1h.x, b1h.y, b1h.z, b1h.w};
    acc0 = __builtin_amdgcn_mfma_f32_16x16x32_bf16(a, bf0, acc0, 0, 0, 0);
    acc1 = __builtin_amdgcn_mfma_f32_16x16x32_bf16(a, bf1, acc1, 0, 0, 0);
  }
  const int c0 = cb + (l & 15);
#pragma unroll
  for (int r = 0; r < 4; ++r) {
    int row = rb + (l >> 4) * 4 + r;
    size_t gi = (size_t)(r0 + row) * 64;
    CT[row][c0] = acc0[r] + b2[c0] + res[gi + c0];
    CT[row][c0 + 16] = acc1[r] + b2[c0 + 16] + res[gi + c0 + 16];
  }
  __syncthreads();
  const int row = tid >> 3, sub = tid & 7;
  float v[8];
#pragma unroll
  for (int i = 0; i < 8; ++i) v[i] = CT[row][sub * 8 + i];
  float s = 0.f;
#pragma unroll
  for (int i = 0; i < 8; ++i) s += v[i];
#pragma unroll
  for (int off = 1; off < 8; off <<= 1) s += __shfl_xor(s, off, 64);
  float mean = s * (1.f / 64.f);
  float q = 0.f;
#pragma unroll
  for (int i = 0; i < 8; ++i) {
    float d = v[i] - mean;
    q += d * d;
  }
#pragma unroll
  for (int off = 1; off < 8; off <<= 1) q += __shfl_xor(q, off, 64);
  float rstd = rsqrtf(q * (1.f / 64.f) + 1e-5f);
  float r4[8];
#pragma unroll
  for (int i = 0; i < 8; ++i)
    r4[i] = (v[i] - mean) * rstd * g[sub * 8 + i] + be[sub * 8 + i];
  float* op = out + (size_t)(r0 + row) * 64 + sub * 8;
  *(float4*)op = (float4){r4[0], r4[1], r4[2], r4[3]};
  *(float4*)(op + 4) = (float4){r4[4], r4[5], r4[6], r4[7]};
}

// ---------------------------------------------------------------------------
extern "C" void kernel_launch(void* const* d_in, const int* in_sizes, int n_in,
                              void* d_out, int out_size, void* d_ws,
                              size_t ws_size, hipStream_t stream) {
  const float* x = (const float*)d_in[0];
  const float* adj = (const float*)d_in[1];
  const float* W_gp = (const float*)d_in[2];
  const float* b_gp = (const float*)d_in[3];
  const float* Wq_s = (const float*)d_in[4];
  const float* Wk_s = (const float*)d_in[5];
  const float* Wv_s = (const float*)d_in[6];
  const float* Wo_s = (const float*)d_in[7];
  const float* bq_s = (const float*)d_in[8];
  const float* bk_s = (const float*)d_in[9];
  const float* bv_s = (const float*)d_in[10];
  const float* bo_s = (const float*)d_in[11];
  const float* g_s = (const float*)d_in[12];
  const float* be_s = (const float*)d_in[13];
  const float* Wq_t = (const float*)d_in[14];
  const float* Wk_t = (const float*)d_in[15];
  const float* Wv_t = (const float*)d_in[16];
  const float* Wo_t = (const float*)d_in[17];
  const float* bq_t = (const float*)d_in[18];
  const float* bk_t = (const float*)d_in[19];
  const float* bv_t = (const float*)d_in[20];
  const float* bo_t = (const float*)d_in[21];
  const float* g_t = (const float*)d_in[22];
  const float* be_t = (const float*)d_in[23];
  const float* W1 = (const float*)d_in[24];
  const float* b1 = (const float*)d_in[25];
  const float* W2 = (const float*)d_in[26];
  const float* b2 = (const float*)d_in[27];
  const float* g1 = (const float*)d_in[28];
  const float* be1 = (const float*)d_in[29];
  const float* g2 = (const float*)d_in[30];
  const float* be2 = (const float*)d_in[31];
  float* out = (float*)d_out;

  float* ws = (float*)d_ws;
  const size_t U = (size_t)NR * 64;  // 1,228,800 floats
  float* A = ws + 0 * U;
  float* Bb = ws + 1 * U;
  float* C = ws + 2 * U;
  float* D = ws + 3 * U;
  float* P = ws + 4 * U;
  // bf16 QKV overlays (first half of A/Bb/C)
  unsigned short* QB = (unsigned short*)A;
  unsigned short* KB = (unsigned short*)Bb;
  unsigned short* VB = (unsigned short*)C;
  // 5U..7U: PB (bf16, pre-FFN) then HIDB (bf16 NRx256, FFN phase)
  unsigned short* PB = (unsigned short*)(ws + 5 * U);
  unsigned short* HIDB = (unsigned short*)(ws + 5 * U);
  unsigned short* LNB = (unsigned short*)(ws + 7 * U);            // 0.5U
  unsigned short* W1B = (unsigned short*)(ws + 7 * U + U / 2);    // 16384 sh
  unsigned short* W2B = W1B + 16384;
  unsigned short* HB0 = (unsigned short*)(ws + 9 * U);
  unsigned short* HB1 = (unsigned short*)(ws + 9 * U + U / 2);
  unsigned short* XSB = HB1;
  unsigned short* ADJB = (unsigned short*)(ws + 10 * U);          // 640000 fl
  unsigned short* WB = (unsigned short*)(ws + 10 * U + 650240);   // 7*4096 sh

  dim3 blk(256);
  // 0) conversions
  k_w2bf<<<dim3(16, 7), blk, 0, stream>>>(Wq_s, Wk_s, Wv_s, Wq_t, Wk_t, Wv_t,
                                          W_gp, WB);
  k_f2bf<<<64, blk, 0, stream>>>(W1, W1B, 16384);
  k_f2bf<<<64, blk, 0, stream>>>(W2, W2B, 16384);
  k_adjbf<<<(NB * NN * NN / 4 + 255) / 256, blk, 0, stream>>>(adj, ADJB);
  // 1) accident scale -> XSB ; graph linear -> HB0 (bf16)
  k_xscale<<<NR / 4, blk, 0, stream>>>(x, XSB);
  k_lin64_mfma<<<NR / 32, blk, 0, stream>>>(XSB, WB + 6 * 4096, b_gp, HB0);
  // 2) 3 MFMA propagation steps; residual fused into last -> P (f32) + PB
  k_prop_mfma<false><<<NBS * 25, blk, 0, stream>>>(ADJB, HB0, x, HB1, P, PB);
  k_prop_mfma<false><<<NBS * 25, blk, 0, stream>>>(ADJB, HB1, x, HB0, P, PB);
  k_prop_mfma<true><<<NBS * 25, blk, 0, stream>>>(ADJB, HB0, x, HB1, P, PB);
  // 3) spatial QKV (bf16 out) -> attn -> proj+LN -> A (f32) + PB (bf16)
  k_qkv_mfma<true><<<NR / 32, blk, 0, stream>>>(PB, WB, WB + 4096, WB + 8192,
                                                bq_s, bk_s, bv_s, QB, KB, VB);
  k_sattn_mfma<<<dim3(NBS, HEADS, 13), blk, 0, stream>>>(QB, KB, VB, D);
  k_projln<<<NR / 4, blk, 0, stream>>>(D, Wo_s, bo_s, P, g_s, be_s, A, PB);
  // 4) temporal QKV (f32 out) -> Bb,C,D ; attn -> P ; proj+LN -> Bb (res = A)
  k_qkv_mfma<false><<<NR / 32, blk, 0, stream>>>(PB, WB + 12288, WB + 16384,
                                                 WB + 20480, bq_t, bk_t, bv_t,
                                                 Bb, C, D);
  k_tattn<<<NB * NN, blk, 0, stream>>>(Bb, C, D, P);
  k_projln<<<NR / 4, blk, 0, stream>>>(P, Wo_t, bo_t, A, g_t, be_t, Bb,
                                       (unsigned short*)nullptr);
  // 5) FFN: LN1 -> LNB (bf16) ; ffn1 -> HIDB ; ffn2 + res + LN -> out
  k_ln<<<NR / 4, blk, 0, stream>>>(Bb, g1, be1, LNB);
  k_ffn1_mfma<<<dim3(NR / 32, 4), blk, 0, stream>>>(LNB, W1B, b1, HIDB);
  k_ffn2ln_mfma<<<NR / 32, blk, 0, stream>>>(HIDB, W2B, b2, Bb, g2, be2, out);
}

// Round 6
// 173.923 us; speedup vs baseline: 3.8324x; 1.4280x over previous
//
#include <hip/hip_runtime.h>
#include <hip/hip_bf16.h>

#define NB 2
#define NS 12
#define NN 800
#define HEADS 8
#define DH 8
#define NBS (NB*NS)        // 24
#define NR (NB*NS*NN)      // 19200 rows

typedef __attribute__((ext_vector_type(4))) float f32x4;
typedef __attribute__((ext_vector_type(4))) short s16x4;
typedef __attribute__((ext_vector_type(8))) short s16x8;

static __device__ __forceinline__ unsigned short f2bf(float f) {
  union { float f; unsigned u; } v; v.f = f;
  unsigned r = (v.u + 0x7FFFu + ((v.u >> 16) & 1u)) >> 16;
  return (unsigned short)r;
}
static __device__ __forceinline__ float bf2f(unsigned short u) {
  union { unsigned u; float f; } v;
  v.u = ((unsigned)u) << 16;
  return v.f;
}
static __device__ __forceinline__ float fexp2(float x) {
  return __builtin_amdgcn_exp2f(x);  // v_exp_f32
}
static __device__ __forceinline__ unsigned cvtpk_bf16(float a, float b) {
  unsigned r;
  asm("v_cvt_pk_bf16_f32 %0, %1, %2" : "=v"(r) : "v"(a), "v"(b));
  return r;  // low16 = bf16(a), high16 = bf16(b)
}

// ---------------------------------------------------------------------------
// 0a) adj f32 -> bf16
// ---------------------------------------------------------------------------
__global__ __launch_bounds__(256) void k_adjbf(const float* __restrict__ adj,
                                               unsigned short* __restrict__ o) {
  int i = blockIdx.x * 256 + threadIdx.x;
  if (i >= NB * NN * NN / 4) return;
  float4 a = *(const float4*)(adj + (size_t)i * 4);
  ushort4 r;
  r.x = f2bf(a.x); r.y = f2bf(a.y); r.z = f2bf(a.z); r.w = f2bf(a.w);
  *(ushort4*)(o + (size_t)i * 4) = r;
}

// ---------------------------------------------------------------------------
// 0b) 9 64x64 weight matrices f32 -> bf16
// ---------------------------------------------------------------------------
__global__ __launch_bounds__(256) void k_w2bf(
    const float* __restrict__ w0, const float* __restrict__ w1,
    const float* __restrict__ w2, const float* __restrict__ w3,
    const float* __restrict__ w4, const float* __restrict__ w5,
    const float* __restrict__ w6, const float* __restrict__ w7,
    const float* __restrict__ w8, unsigned short* __restrict__ out) {
  const float* ws[9] = {w0, w1, w2, w3, w4, w5, w6, w7, w8};
  int y = blockIdx.y;
  int i = blockIdx.x * 256 + threadIdx.x;
  if (i < 4096) out[y * 4096 + i] = f2bf(ws[y][i]);
}

// ---------------------------------------------------------------------------
// 0c) generic f32 -> bf16 copy
// ---------------------------------------------------------------------------
__global__ __launch_bounds__(256) void k_f2bf(const float* __restrict__ src,
                                              unsigned short* __restrict__ dst,
                                              int n) {
  int i = blockIdx.x * 256 + threadIdx.x;
  if (i < n) dst[i] = f2bf(src[i]);
}

// ---------------------------------------------------------------------------
// 1a) xs = x*(1+0.3*x[..,62]*exp(-x[..,63]/60))  -> bf16 (wave per row)
// ---------------------------------------------------------------------------
__global__ __launch_bounds__(256) void k_xscale(const float* __restrict__ x,
                                                unsigned short* __restrict__ o) {
  int tid = threadIdx.x;
  int lane = tid & 63, w = tid >> 6;
  int row = blockIdx.x * 4 + w;
  float v = x[(size_t)row * 64 + lane];
  float a62 = __shfl(v, 62, 64);
  float a63 = __shfl(v, 63, 64);
  float sf = 1.0f + 0.3f * a62 * __expf(-a63 * (1.0f / 60.0f));
  o[(size_t)row * 64 + lane] = f2bf(v * sf);
}

// ---------------------------------------------------------------------------
// 1b) generic MFMA linear 64->64: out_bf16 = Xb @ Wb + b
// ---------------------------------------------------------------------------
__global__ __launch_bounds__(256) void k_lin64_mfma(
    const unsigned short* __restrict__ Xb, const unsigned short* __restrict__ Wb,
    const float* __restrict__ bias, unsigned short* __restrict__ out) {
  __shared__ unsigned short As[32][36];
  __shared__ unsigned short Bs[64][36];
  const int tid = threadIdx.x;
  const int r0 = blockIdx.x * 32;
  const int w = tid >> 6, l = tid & 63;
  const int rb = (w & 1) * 16, cb = (w >> 1) * 32;
  f32x4 acc0 = {0.f, 0.f, 0.f, 0.f}, acc1 = {0.f, 0.f, 0.f, 0.f};
  const int ar = tid >> 3, ak = (tid & 7) * 4;
  const int bc = tid & 63, bm0 = (tid >> 6) * 4;
  const int k4 = (l >> 4) * 4;
  const int arow = rb + (l & 15);
  const int bcol0 = cb + (l & 15);
  for (int k0 = 0; k0 < 64; k0 += 32) {
    __syncthreads();
    *(s16x4*)&As[ar][ak] = *(const s16x4*)(Xb + (size_t)(r0 + ar) * 64 + k0 + ak);
#pragma unroll
    for (int j = 0; j < 4; ++j) {
      int mp = bm0 + j;
      unsigned lo = Wb[(size_t)(k0 + 2 * mp) * 64 + bc];
      unsigned hi = Wb[(size_t)(k0 + 2 * mp + 1) * 64 + bc];
      *(unsigned*)&Bs[bc][2 * mp] = lo | (hi << 16);
    }
    __syncthreads();
    s16x4 alo = *(const s16x4*)&As[arow][k4];
    s16x4 ahi = *(const s16x4*)&As[arow][k4 + 16];
    s16x8 a = {alo.x, alo.y, alo.z, alo.w, ahi.x, ahi.y, ahi.z, ahi.w};
    s16x4 b0l = *(const s16x4*)&Bs[bcol0][k4];
    s16x4 b0h = *(const s16x4*)&Bs[bcol0][k4 + 16];
    s16x8 bf0 = {b0l.x, b0l.y, b0l.z, b0l.w, b0h.x, b0h.y, b0h.z, b0h.w};
    s16x4 b1l = *(const s16x4*)&Bs[bcol0 + 16][k4];
    s16x4 b1h = *(const s16x4*)&Bs[bcol0 + 16][k4 + 16];
    s16x8 bf1 = {b1l.x, b1l.y, b1l.z, b1l.w, b1h.x, b1h.y, b1h.z, b1h.w};
    acc0 = __builtin_amdgcn_mfma_f32_16x16x32_bf16(a, bf0, acc0, 0, 0, 0);
    acc1 = __builtin_amdgcn_mfma_f32_16x16x32_bf16(a, bf1, acc1, 0, 0, 0);
  }
  const int c0 = cb + (l & 15);
  float b0 = bias[c0], b1 = bias[c0 + 16];
#pragma unroll
  for (int r = 0; r < 4; ++r) {
    int row = r0 + rb + (l >> 4) * 4 + r;
    out[(size_t)row * 64 + c0] = f2bf(acc0[r] + b0);
    out[(size_t)row * 64 + c0 + 16] = f2bf(acc1[r] + b1);
  }
}

// ---------------------------------------------------------------------------
// 2) MFMA graph propagation: h' = relu(adj @ h)
//    LAST: pout = relu(adj@h) + x (f32)  AND  pbout = bf16(pout)
// ---------------------------------------------------------------------------
template <bool LAST>
__global__ __launch_bounds__(256) void k_prop_mfma(
    const unsigned short* __restrict__ adjB,
    const unsigned short* __restrict__ hin,
    const float* __restrict__ x,
    unsigned short* __restrict__ hout,
    float* __restrict__ pout,
    unsigned short* __restrict__ pbout) {
  __shared__ unsigned short As[32][36];
  __shared__ unsigned short Bs[64][36];
  const int tid = threadIdx.x;
  const int bid = blockIdx.x;
  const int bs = bid / 25, mt = bid % 25;
  const int b = bs / NS;
  const int n0 = mt * 32;
  const unsigned short* abase = adjB + (size_t)b * NN * NN + (size_t)n0 * NN;
  const unsigned short* hbase = hin + (size_t)bs * NN * 64;
  const int w = tid >> 6, l = tid & 63;
  const int rb = (w & 1) * 16;
  const int cb = (w >> 1) * 32;
  f32x4 acc0 = {0.f, 0.f, 0.f, 0.f}, acc1 = {0.f, 0.f, 0.f, 0.f};
  const int ar = tid >> 3, ak = (tid & 7) * 4;
  const int bc = tid & 63, bm0 = (tid >> 6) * 4;
  const int k4 = (l >> 4) * 4;
  const int arow = rb + (l & 15);
  const int bcol0 = cb + (l & 15);
  for (int m0 = 0; m0 < NN; m0 += 32) {
    __syncthreads();
    *(s16x4*)&As[ar][ak] =
        *(const s16x4*)(abase + (size_t)ar * NN + m0 + ak);
#pragma unroll
    for (int j = 0; j < 4; ++j) {
      int mp = bm0 + j;
      unsigned lo = hbase[(size_t)(m0 + 2 * mp) * 64 + bc];
      unsigned hi = hbase[(size_t)(m0 + 2 * mp + 1) * 64 + bc];
      *(unsigned*)&Bs[bc][2 * mp] = lo | (hi << 16);
    }
    __syncthreads();
    s16x4 alo = *(const s16x4*)&As[arow][k4];
    s16x4 ahi = *(const s16x4*)&As[arow][k4 + 16];
    s16x8 a = {alo.x, alo.y, alo.z, alo.w, ahi.x, ahi.y, ahi.z, ahi.w};
    s16x4 b0l = *(const s16x4*)&Bs[bcol0][k4];
    s16x4 b0h = *(const s16x4*)&Bs[bcol0][k4 + 16];
    s16x8 bf0 = {b0l.x, b0l.y, b0l.z, b0l.w, b0h.x, b0h.y, b0h.z, b0h.w};
    s16x4 b1l = *(const s16x4*)&Bs[bcol0 + 16][k4];
    s16x4 b1h = *(const s16x4*)&Bs[bcol0 + 16][k4 + 16];
    s16x8 bf1 = {b1l.x, b1l.y, b1l.z, b1l.w, b1h.x, b1h.y, b1h.z, b1h.w};
    acc0 = __builtin_amdgcn_mfma_f32_16x16x32_bf16(a, bf0, acc0, 0, 0, 0);
    acc1 = __builtin_amdgcn_mfma_f32_16x16x32_bf16(a, bf1, acc1, 0, 0, 0);
  }
#pragma unroll
  for (int r = 0; r < 4; ++r) {
    int n = n0 + rb + (l >> 4) * 4 + r;
    int c0 = cb + (l & 15);
    float v0 = fmaxf(acc0[r], 0.f);
    float v1 = fmaxf(acc1[r], 0.f);
    size_t i0 = ((size_t)bs * NN + n) * 64 + c0;
    size_t i1 = i0 + 16;
    if (LAST) {
      float p0 = v0 + x[i0], p1 = v1 + x[i1];
      pout[i0] = p0;
      pout[i1] = p1;
      pbout[i0] = f2bf(p0);
      pbout[i1] = f2bf(p1);
    } else {
      hout[i0] = f2bf(v0);
      hout[i1] = f2bf(v1);
    }
  }
}

// ---------------------------------------------------------------------------
// 3) MFMA fused QKV; BFOUT: bf16 outputs (spatial), else f32 (temporal)
// ---------------------------------------------------------------------------
template <bool BFOUT>
__global__ __launch_bounds__(256) void k_qkv_mfma(
    const unsigned short* __restrict__ Xb,
    const unsigned short* __restrict__ Wq,
    const unsigned short* __restrict__ Wk,
    const unsigned short* __restrict__ Wv,
    const float* __restrict__ bq, const float* __restrict__ bk,
    const float* __restrict__ bv,
    void* __restrict__ Qo, void* __restrict__ Ko, void* __restrict__ Vo) {
  __shared__ unsigned short As[32][36];
  __shared__ unsigned short Bs[3][64][36];
  const int tid = threadIdx.x;
  const int r0 = blockIdx.x * 32;
  const int w = tid >> 6, l = tid & 63;
  const int rb = (w & 1) * 16;
  const int cb = (w >> 1) * 32;
  f32x4 acc[3][2];
#pragma unroll
  for (int i = 0; i < 3; ++i)
#pragma unroll
    for (int j = 0; j < 2; ++j) acc[i][j] = (f32x4){0.f, 0.f, 0.f, 0.f};
  const unsigned short* Wm[3] = {Wq, Wk, Wv};
  const int ar = tid >> 3, ak = (tid & 7) * 4;
  const int bc = tid & 63, bm0 = (tid >> 6) * 4;
  const int k4 = (l >> 4) * 4;
  const int arow = rb + (l & 15);
  const int bcol0 = cb + (l & 15);
  for (int k0 = 0; k0 < 64; k0 += 32) {
    __syncthreads();
    *(s16x4*)&As[ar][ak] =
        *(const s16x4*)(Xb + (size_t)(r0 + ar) * 64 + k0 + ak);
#pragma unroll
    for (int wm = 0; wm < 3; ++wm) {
#pragma unroll
      for (int j = 0; j < 4; ++j) {
        int mp = bm0 + j;
        unsigned lo = Wm[wm][(size_t)(k0 + 2 * mp) * 64 + bc];
        unsigned hi = Wm[wm][(size_t)(k0 + 2 * mp + 1) * 64 + bc];
        *(unsigned*)&Bs[wm][bc][2 * mp] = lo | (hi << 16);
      }
    }
    __syncthreads();
    s16x4 alo = *(const s16x4*)&As[arow][k4];
    s16x4 ahi = *(const s16x4*)&As[arow][k4 + 16];
    s16x8 a = {alo.x, alo.y, alo.z, alo.w, ahi.x, ahi.y, ahi.z, ahi.w};
#pragma unroll
    for (int wm = 0; wm < 3; ++wm) {
      s16x4 b0l = *(const s16x4*)&Bs[wm][bcol0][k4];
      s16x4 b0h = *(const s16x4*)&Bs[wm][bcol0][k4 + 16];
      s16x8 bf0 = {b0l.x, b0l.y, b0l.z, b0l.w, b0h.x, b0h.y, b0h.z, b0h.w};
      s16x4 b1l = *(const s16x4*)&Bs[wm][bcol0 + 16][k4];
      s16x4 b1h = *(const s16x4*)&Bs[wm][bcol0 + 16][k4 + 16];
      s16x8 bf1 = {b1l.x, b1l.y, b1l.z, b1l.w, b1h.x, b1h.y, b1h.z, b1h.w};
      acc[wm][0] = __builtin_amdgcn_mfma_f32_16x16x32_bf16(a, bf0, acc[wm][0], 0, 0, 0);
      acc[wm][1] = __builtin_amdgcn_mfma_f32_16x16x32_bf16(a, bf1, acc[wm][1], 0, 0, 0);
    }
  }
  const float* bm[3] = {bq, bk, bv};
  const int c0 = cb + (l & 15);
#pragma unroll
  for (int wm = 0; wm < 3; ++wm) {
    float b0 = bm[wm][c0], b1 = bm[wm][c0 + 16];
#pragma unroll
    for (int r = 0; r < 4; ++r) {
      int row = r0 + rb + (l >> 4) * 4 + r;
      float v0 = acc[wm][0][r] + b0;
      float v1 = acc[wm][1][r] + b1;
      if (BFOUT) {
        unsigned short* Om = (unsigned short*)(wm == 0 ? Qo : (wm == 1 ? Ko : Vo));
        Om[(size_t)row * 64 + c0] = f2bf(v0);
        Om[(size_t)row * 64 + c0 + 16] = f2bf(v1);
      } else {
        float* Om = (float*)(wm == 0 ? Qo : (wm == 1 ? Ko : Vo));
        Om[(size_t)row * 64 + c0] = v0;
        Om[(size_t)row * 64 + c0 + 16] = v1;
      }
    }
  }
}

// ---------------------------------------------------------------------------
// 4) spatial attention v2: swapped QK^T (S^T = K·Q^T) + MFMA PV (O^T = V^T·P^T)
//    Lane holds scores for query=lane&15, keys=(lane>>4)*4+r — which is
//    exactly the PV B-fragment layout. 4 waves/block, 16 queries/wave.
// ---------------------------------------------------------------------------
#define SC_LOG2 (0.35355339059327373f * 1.44269504088896f)

__global__ __launch_bounds__(256) void k_sattn2(
    const unsigned short* __restrict__ Qb,
    const unsigned short* __restrict__ Kb,
    const unsigned short* __restrict__ Vb,
    unsigned short* __restrict__ OB) {
  __shared__ unsigned short Ks[800][8];
  __shared__ unsigned short Vt[25 * 256];  // [t][d][kk ^ swizzle]
  const int bs = blockIdx.x, h = blockIdx.y;
  const int tid = threadIdx.x;
  const size_t base = (size_t)bs * NN * 64 + h * DH;
  for (int r = tid; r < NN; r += 256) {
    s16x4 k0 = *(const s16x4*)(Kb + base + (size_t)r * 64);
    s16x4 k1 = *(const s16x4*)(Kb + base + (size_t)r * 64 + 4);
    *(s16x4*)&Ks[r][0] = k0;
    *(s16x4*)&Ks[r][4] = k1;
    s16x4 v0 = *(const s16x4*)(Vb + base + (size_t)r * 64);
    s16x4 v1 = *(const s16x4*)(Vb + base + (size_t)r * 64 + 4);
    int t = r >> 5, kk = r & 31;
    int c = kk >> 2, lo = kk & 3;
    unsigned short vv[8] = {(unsigned short)v0.x, (unsigned short)v0.y,
                            (unsigned short)v0.z, (unsigned short)v0.w,
                            (unsigned short)v1.x, (unsigned short)v1.y,
                            (unsigned short)v1.z, (unsigned short)v1.w};
#pragma unroll
    for (int d = 0; d < 8; ++d)
      Vt[t * 256 + d * 32 + (((c ^ d) & 7) << 2) + lo] = vv[d];
  }
  __syncthreads();
  const int w = tid >> 6, l = tid & 63;
  const int q0 = blockIdx.z * 64 + w * 16;
  if (q0 >= NN) return;
  const int r15 = l & 15, g = l >> 4;
  // Q fragment (B operand): col=query=r15, k-slots g*4+{0..3}
  s16x8 qf = {0, 0, 0, 0, 0, 0, 0, 0};
  if (g < 2) {
    s16x4 qv = *(const s16x4*)(Qb + base + (size_t)(q0 + r15) * 64 + g * 4);
    qf[0] = qv.x; qf[1] = qv.y; qf[2] = qv.z; qf[3] = qv.w;
  }
  // Vt lane byte-chunk offsets (swizzled)
  const int dd = r15;
  const int off1 = dd * 32 + ((g ^ dd) & 7) * 4;
  const int off2 = dd * 32 + (((4 + g) ^ dd) & 7) * 4;
  float m = -1e30f, ls = 0.f;
  f32x4 acc = {0.f, 0.f, 0.f, 0.f};
  const f32x4 zero4 = {0.f, 0.f, 0.f, 0.f};
  for (int t = 0; t < 25; ++t) {
    s16x8 kfa = {0, 0, 0, 0, 0, 0, 0, 0};
    s16x8 kfb = {0, 0, 0, 0, 0, 0, 0, 0};
    if (g < 2) {
      s16x4 ka = *(const s16x4*)&Ks[t * 32 + r15][g * 4];
      kfa[0] = ka.x; kfa[1] = ka.y; kfa[2] = ka.z; kfa[3] = ka.w;
      s16x4 kb2 = *(const s16x4*)&Ks[t * 32 + 16 + r15][g * 4];
      kfb[0] = kb2.x; kfb[1] = kb2.y; kfb[2] = kb2.z; kfb[3] = kb2.w;
    }
    f32x4 sA = __builtin_amdgcn_mfma_f32_16x16x32_bf16(kfa, qf, zero4, 0, 0, 0);
    f32x4 sB = __builtin_amdgcn_mfma_f32_16x16x32_bf16(kfb, qf, zero4, 0, 0, 0);
    // tile max over this lane's 8 keys, then across the 4 lane-groups
    float tm = fmaxf(fmaxf(fmaxf(sA[0], sA[1]), fmaxf(sA[2], sA[3])),
                     fmaxf(fmaxf(sB[0], sB[1]), fmaxf(sB[2], sB[3])));
    tm = fmaxf(tm, __shfl_xor(tm, 16, 64));
    tm = fmaxf(tm, __shfl_xor(tm, 32, 64));
    float mn = fmaxf(m, tm * SC_LOG2);
    float corr = fexp2(m - mn);
    m = mn;
    ls *= corr;
    acc[0] *= corr; acc[1] *= corr; acc[2] *= corr; acc[3] *= corr;
    float p[8];
#pragma unroll
    for (int r = 0; r < 4; ++r) {
      p[r] = fexp2(fmaf(sA[r], SC_LOG2, -m));
      p[4 + r] = fexp2(fmaf(sB[r], SC_LOG2, -m));
    }
    ls += ((p[0] + p[1]) + (p[2] + p[3])) + ((p[4] + p[5]) + (p[6] + p[7]));
    union { unsigned u[4]; s16x8 v; } pu;
    pu.u[0] = cvtpk_bf16(p[0], p[1]);
    pu.u[1] = cvtpk_bf16(p[2], p[3]);
    pu.u[2] = cvtpk_bf16(p[4], p[5]);
    pu.u[3] = cvtpk_bf16(p[6], p[7]);
    // V^T fragment (A operand): row=d=lane&15, k-slots = keys
    s16x8 vf = {0, 0, 0, 0, 0, 0, 0, 0};
    if (dd < 8) {
      s16x4 va = *(const s16x4*)&Vt[t * 256 + off1];
      s16x4 vb = *(const s16x4*)&Vt[t * 256 + off2];
      vf[0] = va.x; vf[1] = va.y; vf[2] = va.z; vf[3] = va.w;
      vf[4] = vb.x; vf[5] = vb.y; vf[6] = vb.z; vf[7] = vb.w;
    }
    acc = __builtin_amdgcn_mfma_f32_16x16x32_bf16(vf, pu.v, acc, 0, 0, 0);
  }
  ls += __shfl_xor(ls, 16, 64);
  ls += __shfl_xor(ls, 32, 64);
  float inv = 1.f / ls;
  if (g < 2) {
#pragma unroll
    for (int r = 0; r < 4; ++r) {
      int d = g * 4 + r;  // D row = d
      OB[base + (size_t)(q0 + r15) * 64 + d] = f2bf(acc[r] * inv);
    }
  }
}

// ---------------------------------------------------------------------------
// 5) MFMA proj + residual + LN: out = LN(Xb@W + b + res)  (K=64)
//    BF2: also emit bf16 copy.
// ---------------------------------------------------------------------------
template <bool BF2>
__global__ __launch_bounds__(256) void k_projln_mfma(
    const unsigned short* __restrict__ Xb,
    const unsigned short* __restrict__ Wb,
    const float* __restrict__ bias, const float* __restrict__ res,
    const float* __restrict__ g, const float* __restrict__ be,
    float* __restrict__ out, unsigned short* __restrict__ bfout) {
  __shared__ unsigned short As[32][36];
  __shared__ unsigned short Bs[64][36];
  __shared__ float CT[32][68];
  const int tid = threadIdx.x;
  const int r0 = blockIdx.x * 32;
  const int w = tid >> 6, l = tid & 63;
  const int rb = (w & 1) * 16, cb = (w >> 1) * 32;
  f32x4 acc0 = {0.f, 0.f, 0.f, 0.f}, acc1 = {0.f, 0.f, 0.f, 0.f};
  const int ar = tid >> 3, ak = (tid & 7) * 4;
  const int bc = tid & 63, bm0 = (tid >> 6) * 4;
  const int k4 = (l >> 4) * 4;
  const int arow = rb + (l & 15);
  const int bcol0 = cb + (l & 15);
  for (int k0 = 0; k0 < 64; k0 += 32) {
    __syncthreads();
    *(s16x4*)&As[ar][ak] = *(const s16x4*)(Xb + (size_t)(r0 + ar) * 64 + k0 + ak);
#pragma unroll
    for (int j = 0; j < 4; ++j) {
      int mp = bm0 + j;
      unsigned lo = Wb[(size_t)(k0 + 2 * mp) * 64 + bc];
      unsigned hi = Wb[(size_t)(k0 + 2 * mp + 1) * 64 + bc];
      *(unsigned*)&Bs[bc][2 * mp] = lo | (hi << 16);
    }
    __syncthreads();
    s16x4 alo = *(const s16x4*)&As[arow][k4];
    s16x4 ahi = *(const s16x4*)&As[arow][k4 + 16];
    s16x8 a = {alo.x, alo.y, alo.z, alo.w, ahi.x, ahi.y, ahi.z, ahi.w};
    s16x4 b0l = *(const s16x4*)&Bs[bcol0][k4];
    s16x4 b0h = *(const s16x4*)&Bs[bcol0][k4 + 16];
    s16x8 bf0 = {b0l.x, b0l.y, b0l.z, b0l.w, b0h.x, b0h.y, b0h.z, b0h.w};
    s16x4 b1l = *(const s16x4*)&Bs[bcol0 + 16][k4];
    s16x4 b1h = *(const s16x4*)&Bs[bcol0 + 16][k4 + 16];
    s16x8 bf1 = {b1l.x, b1l.y, b1l.z, b1l.w, b1h.x, b1h.y, b1h.z, b1h.w};
    acc0 = __builtin_amdgcn_mfma_f32_16x16x32_bf16(a, bf0, acc0, 0, 0, 0);
    acc1 = __builtin_amdgcn_mfma_f32_16x16x32_bf16(a, bf1, acc1, 0, 0, 0);
  }
  const int c0 = cb + (l & 15);
#pragma unroll
  for (int r = 0; r < 4; ++r) {
    int row = rb + (l >> 4) * 4 + r;
    size_t gi = (size_t)(r0 + row) * 64;
    CT[row][c0] = acc0[r] + bias[c0] + res[gi + c0];
    CT[row][c0 + 16] = acc1[r] + bias[c0 + 16] + res[gi + c0 + 16];
  }
  __syncthreads();
  const int row = tid >> 3, sub = tid & 7;
  float v[8];
#pragma unroll
  for (int i = 0; i < 8; ++i) v[i] = CT[row][sub * 8 + i];
  float s = 0.f;
#pragma unroll
  for (int i = 0; i < 8; ++i) s += v[i];
#pragma unroll
  for (int off = 1; off < 8; off <<= 1) s += __shfl_xor(s, off, 64);
  float mean = s * (1.f / 64.f);
  float q = 0.f;
#pragma unroll
  for (int i = 0; i < 8; ++i) {
    float ddd = v[i] - mean;
    q += ddd * ddd;
  }
#pragma unroll
  for (int off = 1; off < 8; off <<= 1) q += __shfl_xor(q, off, 64);
  float rstd = rsqrtf(q * (1.f / 64.f) + 1e-5f);
  float r4[8];
#pragma unroll
  for (int i = 0; i < 8; ++i)
    r4[i] = (v[i] - mean) * rstd * g[sub * 8 + i] + be[sub * 8 + i];
  float* op = out + (size_t)(r0 + row) * 64 + sub * 8;
  *(float4*)op = (float4){r4[0], r4[1], r4[2], r4[3]};
  *(float4*)(op + 4) = (float4){r4[4], r4[5], r4[6], r4[7]};
  if (BF2) {
    unsigned short* bp = bfout + (size_t)(r0 + row) * 64 + sub * 8;
#pragma unroll
    for (int i = 0; i < 8; ++i) bp[i] = f2bf(r4[i]);
  }
}

// ---------------------------------------------------------------------------
// 6) temporal attention: one block per (b,n), L = 12; bf16 out
// ---------------------------------------------------------------------------
__global__ __launch_bounds__(256) void k_tattn(const float* __restrict__ Q,
                                               const float* __restrict__ K,
                                               const float* __restrict__ V,
                                               unsigned short* __restrict__ O) {
  int b = blockIdx.x / NN, n = blockIdx.x % NN;
  __shared__ float Qs[12][64], Ks[12][64], Vs[12][64];
  int tid = threadIdx.x;
  for (int i = tid; i < 12 * 64; i += 256) {
    int s = i >> 6, c = i & 63;
    size_t idx = (((size_t)b * NS + s) * NN + n) * 64 + c;
    Qs[s][c] = Q[idx];
    Ks[s][c] = K[idx];
    Vs[s][c] = V[idx];
  }
  __syncthreads();
  for (int wi = tid; wi < 12 * 64; wi += 256) {
    int l = wi >> 6, c = wi & 63;
    int h8 = c & 56;
    float sc[12];
    float mx = -1e30f;
#pragma unroll
    for (int m = 0; m < 12; ++m) {
      float s = 0.f;
#pragma unroll
      for (int d = 0; d < 8; ++d) s += Qs[l][h8 + d] * Ks[m][h8 + d];
      s *= 0.35355339059327373f;
      sc[m] = s;
      mx = fmaxf(mx, s);
    }
    float sum = 0.f;
#pragma unroll
    for (int m = 0; m < 12; ++m) {
      sc[m] = __expf(sc[m] - mx);
      sum += sc[m];
    }
    float inv = 1.f / sum;
    float o = 0.f;
#pragma unroll
    for (int m = 0; m < 12; ++m) o += sc[m] * Vs[m][c];
    size_t idx = (((size_t)b * NS + l) * NN + n) * 64 + c;
    O[idx] = f2bf(o * inv);
  }
}

// ---------------------------------------------------------------------------
// 7) plain LN (wave per row) -> bf16
// ---------------------------------------------------------------------------
__global__ __launch_bounds__(256) void k_ln(const float* __restrict__ X,
                                            const float* __restrict__ g,
                                            const float* __restrict__ be,
                                            unsigned short* __restrict__ out) {
  int tid = threadIdx.x;
  int lane = tid & 63, w = tid >> 6;
  int row = blockIdx.x * 4 + w;
  float acc = X[(size_t)row * 64 + lane];
  float s = acc;
#pragma unroll
  for (int off = 32; off; off >>= 1) s += __shfl_xor(s, off, 64);
  float mean = s * (1.f / 64.f);
  float d = acc - mean;
  float v = d * d;
#pragma unroll
  for (int off = 32; off; off >>= 1) v += __shfl_xor(v, off, 64);
  float rstd = rsqrtf(v * (1.f / 64.f) + 1e-5f);
  out[(size_t)row * 64 + lane] = f2bf(d * rstd * g[lane] + be[lane]);
}

// ---------------------------------------------------------------------------
// 8) FFN1 MFMA: HIDB = bf16(relu(LNB @ W1b + b1)); W1 is 64x256
// ---------------------------------------------------------------------------
__global__ __launch_bounds__(256) void k_ffn1_mfma(
    const unsigned short* __restrict__ Xb,
    const unsigned short* __restrict__ W1b,  // [64][256]
    const float* __restrict__ b1, unsigned short* __restrict__ Hid) {
  __shared__ unsigned short As[32][36];
  __shared__ unsigned short Bs[64][36];
  const int tid = threadIdx.x;
  const int r0 = blockIdx.x * 32;
  const int n0 = blockIdx.y * 64;
  const int w = tid >> 6, l = tid & 63;
  const int rb = (w & 1) * 16, cb = (w >> 1) * 32;
  f32x4 acc0 = {0.f, 0.f, 0.f, 0.f}, acc1 = {0.f, 0.f, 0.f, 0.f};
  const int ar = tid >> 3, ak = (tid & 7) * 4;
  const int bc = tid & 63, bm0 = (tid >> 6) * 4;
  const int k4 = (l >> 4) * 4;
  const int arow = rb + (l & 15);
  const int bcol0 = cb + (l & 15);
  for (int k0 = 0; k0 < 64; k0 += 32) {
    __syncthreads();
    *(s16x4*)&As[ar][ak] = *(const s16x4*)(Xb + (size_t)(r0 + ar) * 64 + k0 + ak);
#pragma unroll
    for (int j = 0; j < 4; ++j) {
      int mp = bm0 + j;
      unsigned lo = W1b[(size_t)(k0 + 2 * mp) * 256 + n0 + bc];
      unsigned hi = W1b[(size_t)(k0 + 2 * mp + 1) * 256 + n0 + bc];
      *(unsigned*)&Bs[bc][2 * mp] = lo | (hi << 16);
    }
    __syncthreads();
    s16x4 alo = *(const s16x4*)&As[arow][k4];
    s16x4 ahi = *(const s16x4*)&As[arow][k4 + 16];
    s16x8 a = {alo.x, alo.y, alo.z, alo.w, ahi.x, ahi.y, ahi.z, ahi.w};
    s16x4 b0l = *(const s16x4*)&Bs[bcol0][k4];
    s16x4 b0h = *(const s16x4*)&Bs[bcol0][k4 + 16];
    s16x8 bf0 = {b0l.x, b0l.y, b0l.z, b0l.w, b0h.x, b0h.y, b0h.z, b0h.w};
    s16x4 b1l = *(const s16x4*)&Bs[bcol0 + 16][k4];
    s16x4 b1h = *(const s16x4*)&Bs[bcol0 + 16][k4 + 16];
    s16x8 bf1 = {b1l.x, b1l.y, b1l.z, b1l.w, b1h.x, b1h.y, b1h.z, b1h.w};
    acc0 = __builtin_amdgcn_mfma_f32_16x16x32_bf16(a, bf0, acc0, 0, 0, 0);
    acc1 = __builtin_amdgcn_mfma_f32_16x16x32_bf16(a, bf1, acc1, 0, 0, 0);
  }
  const int c0 = cb + (l & 15);
  float b0 = b1[n0 + c0], bb1 = b1[n0 + c0 + 16];
#pragma unroll
  for (int r = 0; r < 4; ++r) {
    int row = r0 + rb + (l >> 4) * 4 + r;
    Hid[(size_t)row * 256 + n0 + c0] = f2bf(fmaxf(acc0[r] + b0, 0.f));
    Hid[(size_t)row * 256 + n0 + c0 + 16] = f2bf(fmaxf(acc1[r] + bb1, 0.f));
  }
}

// ---------------------------------------------------------------------------
// 9) FFN2 MFMA + residual + final LN: out = LN(Hid @ W2 + b2 + res)
// ---------------------------------------------------------------------------
__global__ __launch_bounds__(256) void k_ffn2ln_mfma(
    const unsigned short* __restrict__ Hd,   // [NR][256] bf16
    const unsigned short* __restrict__ W2b,  // [256][64] bf16
    const float* __restrict__ b2, const float* __restrict__ res,
    const float* __restrict__ g, const float* __restrict__ be,
    float* __restrict__ out) {
  __shared__ unsigned short As[32][36];
  __shared__ unsigned short Bs[64][36];
  __shared__ float CT[32][68];
  const int tid = threadIdx.x;
  const int r0 = blockIdx.x * 32;
  const int w = tid >> 6, l = tid & 63;
  const int rb = (w & 1) * 16, cb = (w >> 1) * 32;
  f32x4 acc0 = {0.f, 0.f, 0.f, 0.f}, acc1 = {0.f, 0.f, 0.f, 0.f};
  const int ar = tid >> 3, ak = (tid & 7) * 4;
  const int bc = tid & 63, bm0 = (tid >> 6) * 4;
  const int k4 = (l >> 4) * 4;
  const int arow = rb + (l & 15);
  const int bcol0 = cb + (l & 15);
  for (int k0 = 0; k0 < 256; k0 += 32) {
    __syncthreads();
    *(s16x4*)&As[ar][ak] = *(const s16x4*)(Hd + (size_t)(r0 + ar) * 256 + k0 + ak);
#pragma unroll
    for (int j = 0; j < 4; ++j) {
      int mp = bm0 + j;
      unsigned lo = W2b[(size_t)(k0 + 2 * mp) * 64 + bc];
      unsigned hi = W2b[(size_t)(k0 + 2 * mp + 1) * 64 + bc];
      *(unsigned*)&Bs[bc][2 * mp] = lo | (hi << 16);
    }
    __syncthreads();
    s16x4 alo = *(const s16x4*)&As[arow][k4];
    s16x4 ahi = *(const s16x4*)&As[arow][k4 + 16];
    s16x8 a = {alo.x, alo.y, alo.z, alo.w, ahi.x, ahi.y, ahi.z, ahi.w};
    s16x4 b0l = *(const s16x4*)&Bs[bcol0][k4];
    s16x4 b0h = *(const s16x4*)&Bs[bcol0][k4 + 16];
    s16x8 bf0 = {b0l.x, b0l.y, b0l.z, b0l.w, b0h.x, b0h.y, b0h.z, b0h.w};
    s16x4 b1l = *(const s16x4*)&Bs[bcol0 + 16][k4];
    s16x4 b1h = *(const s16x4*)&Bs[bcol0 + 16][k4 + 16];
    s16x8 bf1 = {b1l.x, b1l.y, b1l.z, b1l.w, b1h.x, b1h.y, b1h.z, b1h.w};
    acc0 = __builtin_amdgcn_mfma_f32_16x16x32_bf16(a, bf0, acc0, 0, 0, 0);
    acc1 = __builtin_amdgcn_mfma_f32_16x16x32_bf16(a, bf1, acc1, 0, 0, 0);
  }
  const int c0 = cb + (l & 15);
#pragma unroll
  for (int r = 0; r < 4; ++r) {
    int row = rb + (l >> 4) * 4 + r;
    size_t gi = (size_t)(r0 + row) * 64;
    CT[row][c0] = acc0[r] + b2[c0] + res[gi + c0];
    CT[row][c0 + 16] = acc1[r] + b2[c0 + 16] + res[gi + c0 + 16];
  }
  __syncthreads();
  const int row = tid >> 3, sub = tid & 7;
  float v[8];
#pragma unroll
  for (int i = 0; i < 8; ++i) v[i] = CT[row][sub * 8 + i];
  float s = 0.f;
#pragma unroll
  for (int i = 0; i < 8; ++i) s += v[i];
#pragma unroll
  for (int off = 1; off < 8; off <<= 1) s += __shfl_xor(s, off, 64);
  float mean = s * (1.f / 64.f);
  float q = 0.f;
#pragma unroll
  for (int i = 0; i < 8; ++i) {
    float d = v[i] - mean;
    q += d * d;
  }
#pragma unroll
  for (int off = 1; off < 8; off <<= 1) q += __shfl_xor(q, off, 64);
  float rstd = rsqrtf(q * (1.f / 64.f) + 1e-5f);
  float r4[8];
#pragma unroll
  for (int i = 0; i < 8; ++i)
    r4[i] = (v[i] - mean) * rstd * g[sub * 8 + i] + be[sub * 8 + i];
  float* op = out + (size_t)(r0 + row) * 64 + sub * 8;
  *(float4*)op = (float4){r4[0], r4[1], r4[2], r4[3]};
  *(float4*)(op + 4) = (float4){r4[4], r4[5], r4[6], r4[7]};
}

// ---------------------------------------------------------------------------
extern "C" void kernel_launch(void* const* d_in, const int* in_sizes, int n_in,
                              void* d_out, int out_size, void* d_ws,
                              size_t ws_size, hipStream_t stream) {
  const float* x = (const float*)d_in[0];
  const float* adj = (const float*)d_in[1];
  const float* W_gp = (const float*)d_in[2];
  const float* b_gp = (const float*)d_in[3];
  const float* Wq_s = (const float*)d_in[4];
  const float* Wk_s = (const float*)d_in[5];
  const float* Wv_s = (const float*)d_in[6];
  const float* Wo_s = (const float*)d_in[7];
  const float* bq_s = (const float*)d_in[8];
  const float* bk_s = (const float*)d_in[9];
  const float* bv_s = (const float*)d_in[10];
  const float* bo_s = (const float*)d_in[11];
  const float* g_s = (const float*)d_in[12];
  const float* be_s = (const float*)d_in[13];
  const float* Wq_t = (const float*)d_in[14];
  const float* Wk_t = (const float*)d_in[15];
  const float* Wv_t = (const float*)d_in[16];
  const float* Wo_t = (const float*)d_in[17];
  const float* bq_t = (const float*)d_in[18];
  const float* bk_t = (const float*)d_in[19];
  const float* bv_t = (const float*)d_in[20];
  const float* bo_t = (const float*)d_in[21];
  const float* g_t = (const float*)d_in[22];
  const float* be_t = (const float*)d_in[23];
  const float* W1 = (const float*)d_in[24];
  const float* b1 = (const float*)d_in[25];
  const float* W2 = (const float*)d_in[26];
  const float* b2 = (const float*)d_in[27];
  const float* g1 = (const float*)d_in[28];
  const float* be1 = (const float*)d_in[29];
  const float* g2 = (const float*)d_in[30];
  const float* be2 = (const float*)d_in[31];
  float* out = (float*)d_out;

  float* ws = (float*)d_ws;
  const size_t U = (size_t)NR * 64;  // 1,228,800 floats
  float* A = ws + 0 * U;
  float* Bb = ws + 1 * U;
  float* C = ws + 2 * U;
  float* D = ws + 3 * U;
  float* P = ws + 4 * U;
  // bf16 overlays
  unsigned short* QB = (unsigned short*)A;
  unsigned short* KB = (unsigned short*)Bb;
  unsigned short* VB = (unsigned short*)C;
  unsigned short* OBuf = (unsigned short*)D;  // sattn out (bf16)
  unsigned short* PB = (unsigned short*)(ws + 5 * U);
  unsigned short* HIDB = (unsigned short*)(ws + 5 * U);
  unsigned short* LNB = (unsigned short*)(ws + 7 * U);  // 0.5U; also TB
  unsigned short* TB = LNB;
  unsigned short* W1B = (unsigned short*)(ws + 7 * U + U / 2);
  unsigned short* W2B = W1B + 16384;
  unsigned short* HB0 = (unsigned short*)(ws + 9 * U);
  unsigned short* HB1 = (unsigned short*)(ws + 9 * U + U / 2);
  unsigned short* XSB = HB1;
  unsigned short* ADJB = (unsigned short*)(ws + 10 * U);
  unsigned short* WB = (unsigned short*)(ws + 10 * U + 650240);  // 9*4096 sh

  dim3 blk(256);
  // 0) conversions
  k_w2bf<<<dim3(16, 9), blk, 0, stream>>>(Wq_s, Wk_s, Wv_s, Wq_t, Wk_t, Wv_t,
                                          W_gp, Wo_s, Wo_t, WB);
  k_f2bf<<<64, blk, 0, stream>>>(W1, W1B, 16384);
  k_f2bf<<<64, blk, 0, stream>>>(W2, W2B, 16384);
  k_adjbf<<<(NB * NN * NN / 4 + 255) / 256, blk, 0, stream>>>(adj, ADJB);
  // 1) accident scale -> XSB ; graph linear -> HB0 (bf16)
  k_xscale<<<NR / 4, blk, 0, stream>>>(x, XSB);
  k_lin64_mfma<<<NR / 32, blk, 0, stream>>>(XSB, WB + 6 * 4096, b_gp, HB0);
  // 2) 3 MFMA propagation steps; residual fused into last -> P (f32) + PB
  k_prop_mfma<false><<<NBS * 25, blk, 0, stream>>>(ADJB, HB0, x, HB1, P, PB);
  k_prop_mfma<false><<<NBS * 25, blk, 0, stream>>>(ADJB, HB1, x, HB0, P, PB);
  k_prop_mfma<true><<<NBS * 25, blk, 0, stream>>>(ADJB, HB0, x, HB1, P, PB);
  // 3) spatial: QKV (bf16) -> sattn2 -> OB ; proj+LN -> A (f32) + PB (bf16)
  k_qkv_mfma<true><<<NR / 32, blk, 0, stream>>>(PB, WB, WB + 4096, WB + 8192,
                                                bq_s, bk_s, bv_s, QB, KB, VB);
  k_sattn2<<<dim3(NBS, HEADS, 13), blk, 0, stream>>>(QB, KB, VB, OBuf);
  k_projln_mfma<true><<<NR / 32, blk, 0, stream>>>(OBuf, WB + 7 * 4096, bo_s, P,
                                                   g_s, be_s, A, PB);
  // 4) temporal: QKV (f32) -> Bb,C,D ; tattn -> TB (bf16) ; proj+LN -> Bb
  k_qkv_mfma<false><<<NR / 32, blk, 0, stream>>>(PB, WB + 12288, WB + 16384,
                                                 WB + 20480, bq_t, bk_t, bv_t,
                                                 Bb, C, D);
  k_tattn<<<NB * NN, blk, 0, stream>>>(Bb, C, D, TB);
  k_projln_mfma<false><<<NR / 32, blk, 0, stream>>>(
      TB, WB + 8 * 4096, bo_t, A, g_t, be_t, Bb, (unsigned short*)nullptr);
  // 5) FFN: LN1 -> LNB (bf16) ; ffn1 -> HIDB ; ffn2 + res + LN -> out
  k_ln<<<NR / 4, blk, 0, stream>>>(Bb, g1, be1, LNB);
  k_ffn1_mfma<<<dim3(NR / 32, 4), blk, 0, stream>>>(LNB, W1B, b1, HIDB);
  k_ffn2ln_mfma<<<NR / 32, blk, 0, stream>>>(HIDB, W2B, b2, Bb, g2, be2, out);
}